// Round 1
// baseline (4351.083 us; speedup 1.0000x reference)
//
#include <hip/hip_runtime.h>
#include <math.h>

#define Bn 8
#define Nn 8192
#define Dn 64
#define Sn 2048
#define NS 32

// ---------------------------------------------------------------------------
// FPS: one block per batch, 1024 threads, 8 points/thread in registers.
// Coordinates staged in LDS for arbitrary-index centroid broadcast.
// Must be bit-exact vs numpy: no FMA contraction, ((dx2+dy2)+dz2), first-max
// tie-breaking (smallest index wins on equal values).
// ---------------------------------------------------------------------------
__global__ __launch_bounds__(1024)
void fps_kernel(const float* __restrict__ xyz, float* __restrict__ newxyz)
{
#pragma clang fp contract(off)
    const int b = blockIdx.x;
    const int tid = threadIdx.x;
    __shared__ float lx[Nn], ly[Nn], lz[Nn];   // 96 KB
    __shared__ int lfar[Sn];                   // 8 KB
    __shared__ float redv[16];
    __shared__ int redi[16];
    __shared__ int sfar;
    const float* xb = xyz + (size_t)b * 3 * Nn;
    float px[8], py[8], pz[8], pd[8];
#pragma unroll
    for (int i = 0; i < 8; ++i) {
        int j = tid + i * 1024;
        float x = xb[j], y = xb[Nn + j], z = xb[2 * Nn + j];
        lx[j] = x; ly[j] = y; lz[j] = z;
        px[i] = x; py[i] = y; pz[i] = z; pd[i] = 1e10f;
    }
    if (tid == 0) lfar[0] = 0;
    __syncthreads();
    int far = 0;
    for (int t = 1; t < Sn; ++t) {
        float cx = lx[far], cy = ly[far], cz = lz[far];
        float best = -1.0f;
        int bidx = 0x7fffffff;
#pragma unroll
        for (int i = 0; i < 8; ++i) {
            float dx = px[i] - cx;
            float dy = py[i] - cy;
            float dz = pz[i] - cz;
            float d = (dx * dx + dy * dy) + dz * dz;
            float nd = fminf(pd[i], d);
            pd[i] = nd;
            if (nd > best) { best = nd; bidx = tid + i * 1024; }  // ascending j => first occurrence kept
        }
        // wave-level argmax (64 lanes), ties -> smaller index
#pragma unroll
        for (int off = 1; off < 64; off <<= 1) {
            float ov = __shfl_xor(best, off);
            int   oi = __shfl_xor(bidx, off);
            if (ov > best || (ov == best && oi < bidx)) { best = ov; bidx = oi; }
        }
        if ((tid & 63) == 0) { redv[tid >> 6] = best; redi[tid >> 6] = bidx; }
        __syncthreads();
        if (tid < 64) {
            float v = (tid < 16) ? redv[tid] : -1.0f;
            int  ix = (tid < 16) ? redi[tid] : 0x7fffffff;
#pragma unroll
            for (int off = 1; off < 16; off <<= 1) {
                float ov = __shfl_xor(v, off);
                int   oi = __shfl_xor(ix, off);
                if (ov > v || (ov == v && oi < ix)) { v = ov; ix = oi; }
            }
            if (tid == 0) { sfar = ix; lfar[t] = ix; }
        }
        __syncthreads();
        far = sfar;
    }
    // write new_xyz [B,3,S]
    for (int t = tid; t < Sn; t += 1024) {
        int j = lfar[t];
        newxyz[(size_t)b * 3 * Sn + t]          = lx[j];
        newxyz[(size_t)b * 3 * Sn + Sn + t]     = ly[j];
        newxyz[(size_t)b * 3 * Sn + 2 * Sn + t] = lz[j];
    }
}

// ---------------------------------------------------------------------------
// Ball query: one wave per (b,s). Scan points in index order, first NS hits;
// pad with first hit. Bit-exact distance + threshold (float)(0.4*0.4).
// ---------------------------------------------------------------------------
__global__ __launch_bounds__(256)
void ballq_kernel(const float* __restrict__ xyz, const float* __restrict__ newxyz,
                  int* __restrict__ idxbuf)
{
#pragma clang fp contract(off)
    const int gw = (blockIdx.x * 256 + threadIdx.x) >> 6;  // global wave id = b*Sn + s
    const int lane = threadIdx.x & 63;
    const int b = gw >> 11;
    const int s = gw & (Sn - 1);
    const float* xb = xyz + (size_t)b * 3 * Nn;
    const float cx = newxyz[(size_t)b * 3 * Sn + s];
    const float cy = newxyz[(size_t)b * 3 * Sn + Sn + s];
    const float cz = newxyz[(size_t)b * 3 * Sn + 2 * Sn + s];
    int* op = idxbuf + (size_t)gw * NS;
    const float R2 = (float)(0.4 * 0.4);   // rounds to 0.15999999642f, matches numpy
    int cnt = 0, first = -1;
    for (int base = 0; base < Nn && cnt < NS; base += 64) {
        int j = base + lane;
        float dx = cx - xb[j];
        float dy = cy - xb[Nn + j];
        float dz = cz - xb[2 * Nn + j];
        float d = (dx * dx + dy * dy) + dz * dz;
        bool hit = d <= R2;
        unsigned long long m = __ballot(hit);
        if (hit) {
            int pos = cnt + __popcll(m & ((1ull << lane) - 1ull));
            if (pos < NS) op[pos] = j;
        }
        if (first < 0 && m != 0ull) first = base + (int)__ffsll((long long)m) - 1;
        cnt += (int)__popcll(m);
    }
    for (int p = cnt + lane; p < NS; p += 64) op[p] = first;  // pad with first hit
}

// ---------------------------------------------------------------------------
// Fold BN (eval) into conv weights: wf = w*scale_c, bias = b - m*scale_c.
// ---------------------------------------------------------------------------
__global__ void prep_kernel(const float* __restrict__ w0, const float* __restrict__ w1,
                            const float* __restrict__ w2,
                            const float* __restrict__ g0, const float* __restrict__ b0,
                            const float* __restrict__ m0, const float* __restrict__ v0,
                            const float* __restrict__ g1, const float* __restrict__ b1,
                            const float* __restrict__ m1, const float* __restrict__ v1,
                            const float* __restrict__ g2, const float* __restrict__ b2,
                            const float* __restrict__ m2, const float* __restrict__ v2,
                            float* __restrict__ wb)
{
    int t = blockIdx.x * blockDim.x + threadIdx.x;
    if (t < 64 * 67) { int c = t / 67; float sc = g0[c] / sqrtf(v0[c] + 1e-5f); wb[t] = w0[t] * sc; }
    if (t < 64)      { float sc = g0[t] / sqrtf(v0[t] + 1e-5f); wb[4288 + t] = b0[t] - m0[t] * sc; }
    if (t < 64 * 64) { int c = t / 64; float sc = g1[c] / sqrtf(v1[c] + 1e-5f); wb[4352 + t] = w1[t] * sc; }
    if (t < 64)      { float sc = g1[t] / sqrtf(v1[t] + 1e-5f); wb[8448 + t] = b1[t] - m1[t] * sc; }
    if (t < 128 * 64){ int c = t / 64; float sc = g2[c] / sqrtf(v2[c] + 1e-5f); wb[8512 + t] = w2[t] * sc; }
    if (t < 128)     { float sc = g2[t] / sqrtf(v2[t] + 1e-5f); wb[16704 + t] = b2[t] - m2[t] * sc; }
}

// ---------------------------------------------------------------------------
// Fused group + MLP(67->64->64->128) + maxpool over 32 samples.
// One thread per (b,s,k) sample; weights via uniform (SGPR) loads; max-reduce
// across the 32 lanes of each half-wave.
// ---------------------------------------------------------------------------
__global__ __launch_bounds__(256)
void mlp_kernel(const float* __restrict__ xyz, const float* __restrict__ points,
                const float* __restrict__ newxyz, const int* __restrict__ idxbuf,
                const float* __restrict__ wb, float* __restrict__ outp)
{
    const int gid = blockIdx.x * 256 + threadIdx.x;
    const int k  = gid & (NS - 1);
    const int bs = gid >> 5;             // b*Sn + s
    const int s  = bs & (Sn - 1);
    const int b  = bs >> 11;
    const int j  = idxbuf[(size_t)bs * NS + k];
    const float* xb = xyz + (size_t)b * 3 * Nn;
    float x0, x1, x2;
    {
#pragma clang fp contract(off)
        x0 = xb[j]          - newxyz[(size_t)b * 3 * Sn + s];
        x1 = xb[Nn + j]     - newxyz[(size_t)b * 3 * Sn + Sn + s];
        x2 = xb[2 * Nn + j] - newxyz[(size_t)b * 3 * Sn + 2 * Sn + s];
    }
    const float* pb = points + (size_t)b * Dn * Nn + j;
    float xf[64];
#pragma unroll
    for (int d = 0; d < 64; ++d) xf[d] = pb[(size_t)d * Nn];

    // layer 0: 67 -> 64
    const float* w0  = wb;
    const float* bb0 = wb + 64 * 67;
    float h0[64];
#pragma unroll 2
    for (int c = 0; c < 64; ++c) {
        const float* wr = w0 + c * 67;
        float a0 = fmaf(wr[0], x0, bb0[c]);
        float a1 = wr[1] * x1;
        float a2 = wr[2] * x2;
        float a3 = 0.0f;
#pragma unroll
        for (int d = 0; d < 64; d += 4) {
            a0 = fmaf(wr[3 + d], xf[d],     a0);
            a1 = fmaf(wr[4 + d], xf[d + 1], a1);
            a2 = fmaf(wr[5 + d], xf[d + 2], a2);
            a3 = fmaf(wr[6 + d], xf[d + 3], a3);
        }
        h0[c] = fmaxf((a0 + a1) + (a2 + a3), 0.0f);
    }
    // layer 1: 64 -> 64
    const float* w1  = wb + 4352;
    const float* bb1 = wb + 8448;
    float h1[64];
#pragma unroll 2
    for (int c = 0; c < 64; ++c) {
        const float* wr = w1 + c * 64;
        float a0 = bb1[c], a1 = 0.f, a2 = 0.f, a3 = 0.f;
#pragma unroll
        for (int d = 0; d < 64; d += 4) {
            a0 = fmaf(wr[d],     h0[d],     a0);
            a1 = fmaf(wr[d + 1], h0[d + 1], a1);
            a2 = fmaf(wr[d + 2], h0[d + 2], a2);
            a3 = fmaf(wr[d + 3], h0[d + 3], a3);
        }
        h1[c] = fmaxf((a0 + a1) + (a2 + a3), 0.0f);
    }
    // layer 2: 64 -> 128, fused max over k (lanes 0..31 / 32..63 groups)
    const float* w2  = wb + 8512;
    const float* bb2 = wb + 16704;
    float* ob = outp + ((size_t)b * 128) * Sn + s;
#pragma unroll 2
    for (int c = 0; c < 128; ++c) {
        const float* wr = w2 + c * 64;
        float a0 = bb2[c], a1 = 0.f, a2 = 0.f, a3 = 0.f;
#pragma unroll
        for (int d = 0; d < 64; d += 4) {
            a0 = fmaf(wr[d],     h1[d],     a0);
            a1 = fmaf(wr[d + 1], h1[d + 1], a1);
            a2 = fmaf(wr[d + 2], h1[d + 2], a2);
            a3 = fmaf(wr[d + 3], h1[d + 3], a3);
        }
        float acc = fmaxf((a0 + a1) + (a2 + a3), 0.0f);
#pragma unroll
        for (int off = 1; off < 32; off <<= 1) acc = fmaxf(acc, __shfl_xor(acc, off));
        if (k == 0) ob[(size_t)c * Sn] = acc;
    }
}

extern "C" void kernel_launch(void* const* d_in, const int* in_sizes, int n_in,
                              void* d_out, int out_size, void* d_ws, size_t ws_size,
                              hipStream_t stream)
{
    const float* xyz    = (const float*)d_in[0];
    const float* points = (const float*)d_in[1];
    const float* w0 = (const float*)d_in[2];
    const float* w1 = (const float*)d_in[3];
    const float* w2 = (const float*)d_in[4];
    const float* g0 = (const float*)d_in[5];
    const float* b0 = (const float*)d_in[6];
    const float* m0 = (const float*)d_in[7];
    const float* v0 = (const float*)d_in[8];
    const float* g1 = (const float*)d_in[9];
    const float* b1 = (const float*)d_in[10];
    const float* m1 = (const float*)d_in[11];
    const float* v1 = (const float*)d_in[12];
    const float* g2 = (const float*)d_in[13];
    const float* b2 = (const float*)d_in[14];
    const float* m2 = (const float*)d_in[15];
    const float* v2 = (const float*)d_in[16];

    float* out = (float*)d_out;                       // new_xyz [8,3,2048] then new_points [8,128,2048]
    float* wb  = (float*)d_ws;                        // 16832 floats of folded weights
    int*   idx = (int*)((char*)d_ws + 128 * 1024);    // [8,2048,32] int

    prep_kernel<<<32, 256, 0, stream>>>(w0, w1, w2, g0, b0, m0, v0,
                                        g1, b1, m1, v1, g2, b2, m2, v2, wb);
    fps_kernel<<<Bn, 1024, 0, stream>>>(xyz, out);
    ballq_kernel<<<(Bn * Sn * 64) / 256, 256, 0, stream>>>(xyz, out, idx);
    mlp_kernel<<<(Bn * Sn * NS) / 256, 256, 0, stream>>>(xyz, points, out, idx, wb,
                                                         out + Bn * 3 * Sn);
}

// Round 2
// 3084.290 us; speedup vs baseline: 1.4107x; 1.4107x over previous
//
#include <hip/hip_runtime.h>
#include <math.h>

#define Bn 8
#define Nn 8192
#define Dn 64
#define Sn 2048
#define NS 32

// ---------------------------------------------------------------------------
// FPS: one block per batch, 512 threads, 16 points/thread (chunked: thread t
// owns indices [16t, 16t+16) so lane order == index order -> cheap tie-break).
// One barrier per iteration via double-buffered per-wave candidates; every
// wave redundantly reduces the 8 candidates (packed u64: valbits<<32 |
// (8191-idx), max = largest value, ties -> smallest index).
// Bit-exact vs numpy: contract off, ((dx2+dy2)+dz2), strict > keeps first max.
// ---------------------------------------------------------------------------
__global__ __launch_bounds__(512)
void fps_kernel(const float* __restrict__ xyz, float* __restrict__ newxyz)
{
#pragma clang fp contract(off)
    const int b = blockIdx.x;
    const int tid = threadIdx.x;
    const int lane = tid & 63;
    const int wv = tid >> 6;                    // 0..7
    __shared__ float4 lxyz[Nn];                 // 128 KB (packed coords)
    __shared__ int lfar[Sn];                    // 8 KB
    __shared__ unsigned long long cand[2][8];
    const float* xb = xyz + (size_t)b * 3 * Nn;
    float px[16], py[16], pz[16], pd[16];
    const int base = tid * 16;
#pragma unroll
    for (int i4 = 0; i4 < 16; i4 += 4) {
        float4 vx = *(const float4*)(xb + base + i4);
        float4 vy = *(const float4*)(xb + Nn + base + i4);
        float4 vz = *(const float4*)(xb + 2 * Nn + base + i4);
        px[i4] = vx.x; px[i4 + 1] = vx.y; px[i4 + 2] = vx.z; px[i4 + 3] = vx.w;
        py[i4] = vy.x; py[i4 + 1] = vy.y; py[i4 + 2] = vy.z; py[i4 + 3] = vy.w;
        pz[i4] = vz.x; pz[i4 + 1] = vz.y; pz[i4 + 2] = vz.z; pz[i4 + 3] = vz.w;
    }
#pragma unroll
    for (int i = 0; i < 16; ++i) {
        lxyz[base + i] = make_float4(px[i], py[i], pz[i], 0.0f);
        pd[i] = 1e10f;
    }
    if (tid == 0) lfar[0] = 0;
    __syncthreads();
    int far = 0;
    for (int t = 1; t < Sn; ++t) {
        float4 cen = lxyz[far];                 // uniform broadcast ds_read_b128
        float best = -1.0f; int bi = 0;
#pragma unroll
        for (int i = 0; i < 16; ++i) {
            float dx = px[i] - cen.x;
            float dy = py[i] - cen.y;
            float dz = pz[i] - cen.z;
            float d = (dx * dx + dy * dy) + dz * dz;
            float nd = fminf(pd[i], d);
            pd[i] = nd;
            if (nd > best) { best = nd; bi = i; }   // strict > => first (smallest i)
        }
        // value-only wave max (6 steps), then recover first-occurrence index
        float wmax = best;
#pragma unroll
        for (int off = 1; off < 64; off <<= 1)
            wmax = fmaxf(wmax, __shfl_xor(wmax, off));
        unsigned long long m = __ballot(best == wmax);
        int srclane = (int)__ffsll((long long)m) - 1;   // lowest lane = smallest chunk
        int gidx = base + bi;
        int widx = __shfl(gidx, srclane);
        if (lane == 0)
            cand[t & 1][wv] = ((unsigned long long)__float_as_uint(wmax) << 32)
                            | (unsigned)(8191 - widx);
        __syncthreads();
        // every wave redundantly reduces the 8 candidates (no 2nd barrier)
        unsigned long long bc = cand[t & 1][0];
#pragma unroll
        for (int w = 1; w < 8; ++w) {
            unsigned long long cc = cand[t & 1][w];
            bc = (cc > bc) ? cc : bc;
        }
        far = 8191 - (int)(bc & 0x3FFFu);
        if (tid == 0) lfar[t] = far;
    }
    __syncthreads();
    for (int t = tid; t < Sn; t += 512) {
        float4 p = lxyz[lfar[t]];
        newxyz[(size_t)b * 3 * Sn + t]          = p.x;
        newxyz[(size_t)b * 3 * Sn + Sn + t]     = p.y;
        newxyz[(size_t)b * 3 * Sn + 2 * Sn + t] = p.z;
    }
}

// ---------------------------------------------------------------------------
// Ball query: one wave per (b,s). Scan points in index order, first NS hits;
// pad with first hit. Bit-exact distance + threshold (float)(0.4*0.4).
// ---------------------------------------------------------------------------
__global__ __launch_bounds__(256)
void ballq_kernel(const float* __restrict__ xyz, const float* __restrict__ newxyz,
                  int* __restrict__ idxbuf)
{
#pragma clang fp contract(off)
    const int gw = (blockIdx.x * 256 + threadIdx.x) >> 6;  // global wave id = b*Sn + s
    const int lane = threadIdx.x & 63;
    const int b = gw >> 11;
    const int s = gw & (Sn - 1);
    const float* xb = xyz + (size_t)b * 3 * Nn;
    const float cx = newxyz[(size_t)b * 3 * Sn + s];
    const float cy = newxyz[(size_t)b * 3 * Sn + Sn + s];
    const float cz = newxyz[(size_t)b * 3 * Sn + 2 * Sn + s];
    int* op = idxbuf + (size_t)gw * NS;
    const float R2 = (float)(0.4 * 0.4);   // rounds to 0.15999999642f, matches numpy
    int cnt = 0, first = -1;
    for (int base = 0; base < Nn && cnt < NS; base += 64) {
        int j = base + lane;
        float dx = cx - xb[j];
        float dy = cy - xb[Nn + j];
        float dz = cz - xb[2 * Nn + j];
        float d = (dx * dx + dy * dy) + dz * dz;
        bool hit = d <= R2;
        unsigned long long m = __ballot(hit);
        if (hit) {
            int pos = cnt + __popcll(m & ((1ull << lane) - 1ull));
            if (pos < NS) op[pos] = j;
        }
        if (first < 0 && m != 0ull) first = base + (int)__ffsll((long long)m) - 1;
        cnt += (int)__popcll(m);
    }
    for (int p = cnt + lane; p < NS; p += 64) op[p] = first;  // pad with first hit
}

// ---------------------------------------------------------------------------
// Fold BN (eval) into conv weights: wf = w*scale_c, bias = b - m*scale_c.
// ---------------------------------------------------------------------------
__global__ void prep_kernel(const float* __restrict__ w0, const float* __restrict__ w1,
                            const float* __restrict__ w2,
                            const float* __restrict__ g0, const float* __restrict__ b0,
                            const float* __restrict__ m0, const float* __restrict__ v0,
                            const float* __restrict__ g1, const float* __restrict__ b1,
                            const float* __restrict__ m1, const float* __restrict__ v1,
                            const float* __restrict__ g2, const float* __restrict__ b2,
                            const float* __restrict__ m2, const float* __restrict__ v2,
                            float* __restrict__ wb)
{
    int t = blockIdx.x * blockDim.x + threadIdx.x;
    if (t < 64 * 67) { int c = t / 67; float sc = g0[c] / sqrtf(v0[c] + 1e-5f); wb[t] = w0[t] * sc; }
    if (t < 64)      { float sc = g0[t] / sqrtf(v0[t] + 1e-5f); wb[4288 + t] = b0[t] - m0[t] * sc; }
    if (t < 64 * 64) { int c = t / 64; float sc = g1[c] / sqrtf(v1[c] + 1e-5f); wb[4352 + t] = w1[t] * sc; }
    if (t < 64)      { float sc = g1[t] / sqrtf(v1[t] + 1e-5f); wb[8448 + t] = b1[t] - m1[t] * sc; }
    if (t < 128 * 64){ int c = t / 64; float sc = g2[c] / sqrtf(v2[c] + 1e-5f); wb[8512 + t] = w2[t] * sc; }
    if (t < 128)     { float sc = g2[t] / sqrtf(v2[t] + 1e-5f); wb[16704 + t] = b2[t] - m2[t] * sc; }
}

// ---------------------------------------------------------------------------
// Fused group + MLP(67->64->64->128) + maxpool over 32 samples.
// One thread per (b,s,k) sample; weights via uniform loads; max-reduce
// across the 32 lanes of each half-wave.
// ---------------------------------------------------------------------------
__global__ __launch_bounds__(256)
void mlp_kernel(const float* __restrict__ xyz, const float* __restrict__ points,
                const float* __restrict__ newxyz, const int* __restrict__ idxbuf,
                const float* __restrict__ wb, float* __restrict__ outp)
{
    const int gid = blockIdx.x * 256 + threadIdx.x;
    const int k  = gid & (NS - 1);
    const int bs = gid >> 5;             // b*Sn + s
    const int s  = bs & (Sn - 1);
    const int b  = bs >> 11;
    const int j  = idxbuf[(size_t)bs * NS + k];
    const float* xb = xyz + (size_t)b * 3 * Nn;
    float x0, x1, x2;
    {
#pragma clang fp contract(off)
        x0 = xb[j]          - newxyz[(size_t)b * 3 * Sn + s];
        x1 = xb[Nn + j]     - newxyz[(size_t)b * 3 * Sn + Sn + s];
        x2 = xb[2 * Nn + j] - newxyz[(size_t)b * 3 * Sn + 2 * Sn + s];
    }
    const float* pb = points + (size_t)b * Dn * Nn + j;
    float xf[64];
#pragma unroll
    for (int d = 0; d < 64; ++d) xf[d] = pb[(size_t)d * Nn];

    // layer 0: 67 -> 64
    const float* w0  = wb;
    const float* bb0 = wb + 64 * 67;
    float h0[64];
#pragma unroll 2
    for (int c = 0; c < 64; ++c) {
        const float* wr = w0 + c * 67;
        float a0 = fmaf(wr[0], x0, bb0[c]);
        float a1 = wr[1] * x1;
        float a2 = wr[2] * x2;
        float a3 = 0.0f;
#pragma unroll
        for (int d = 0; d < 64; d += 4) {
            a0 = fmaf(wr[3 + d], xf[d],     a0);
            a1 = fmaf(wr[4 + d], xf[d + 1], a1);
            a2 = fmaf(wr[5 + d], xf[d + 2], a2);
            a3 = fmaf(wr[6 + d], xf[d + 3], a3);
        }
        h0[c] = fmaxf((a0 + a1) + (a2 + a3), 0.0f);
    }
    // layer 1: 64 -> 64
    const float* w1  = wb + 4352;
    const float* bb1 = wb + 8448;
    float h1[64];
#pragma unroll 2
    for (int c = 0; c < 64; ++c) {
        const float* wr = w1 + c * 64;
        float a0 = bb1[c], a1 = 0.f, a2 = 0.f, a3 = 0.f;
#pragma unroll
        for (int d = 0; d < 64; d += 4) {
            a0 = fmaf(wr[d],     h0[d],     a0);
            a1 = fmaf(wr[d + 1], h0[d + 1], a1);
            a2 = fmaf(wr[d + 2], h0[d + 2], a2);
            a3 = fmaf(wr[d + 3], h0[d + 3], a3);
        }
        h1[c] = fmaxf((a0 + a1) + (a2 + a3), 0.0f);
    }
    // layer 2: 64 -> 128, fused max over k (lanes 0..31 / 32..63 groups)
    const float* w2  = wb + 8512;
    const float* bb2 = wb + 16704;
    float* ob = outp + ((size_t)b * 128) * Sn + s;
#pragma unroll 2
    for (int c = 0; c < 128; ++c) {
        const float* wr = w2 + c * 64;
        float a0 = bb2[c], a1 = 0.f, a2 = 0.f, a3 = 0.f;
#pragma unroll
        for (int d = 0; d < 64; d += 4) {
            a0 = fmaf(wr[d],     h1[d],     a0);
            a1 = fmaf(wr[d + 1], h1[d + 1], a1);
            a2 = fmaf(wr[d + 2], h1[d + 2], a2);
            a3 = fmaf(wr[d + 3], h1[d + 3], a3);
        }
        float acc = fmaxf((a0 + a1) + (a2 + a3), 0.0f);
#pragma unroll
        for (int off = 1; off < 32; off <<= 1) acc = fmaxf(acc, __shfl_xor(acc, off));
        if (k == 0) ob[(size_t)c * Sn] = acc;
    }
}

extern "C" void kernel_launch(void* const* d_in, const int* in_sizes, int n_in,
                              void* d_out, int out_size, void* d_ws, size_t ws_size,
                              hipStream_t stream)
{
    const float* xyz    = (const float*)d_in[0];
    const float* points = (const float*)d_in[1];
    const float* w0 = (const float*)d_in[2];
    const float* w1 = (const float*)d_in[3];
    const float* w2 = (const float*)d_in[4];
    const float* g0 = (const float*)d_in[5];
    const float* b0 = (const float*)d_in[6];
    const float* m0 = (const float*)d_in[7];
    const float* v0 = (const float*)d_in[8];
    const float* g1 = (const float*)d_in[9];
    const float* b1 = (const float*)d_in[10];
    const float* m1 = (const float*)d_in[11];
    const float* v1 = (const float*)d_in[12];
    const float* g2 = (const float*)d_in[13];
    const float* b2 = (const float*)d_in[14];
    const float* m2 = (const float*)d_in[15];
    const float* v2 = (const float*)d_in[16];

    float* out = (float*)d_out;                       // new_xyz [8,3,2048] then new_points [8,128,2048]
    float* wb  = (float*)d_ws;                        // 16832 floats of folded weights
    int*   idx = (int*)((char*)d_ws + 128 * 1024);    // [8,2048,32] int

    prep_kernel<<<32, 256, 0, stream>>>(w0, w1, w2, g0, b0, m0, v0,
                                        g1, b1, m1, v1, g2, b2, m2, v2, wb);
    fps_kernel<<<Bn, 512, 0, stream>>>(xyz, out);
    ballq_kernel<<<(Bn * Sn * 64) / 256, 256, 0, stream>>>(xyz, out, idx);
    mlp_kernel<<<(Bn * Sn * NS) / 256, 256, 0, stream>>>(xyz, points, out, idx, wb,
                                                         out + Bn * 3 * Sn);
}

// Round 3
// 2805.201 us; speedup vs baseline: 1.5511x; 1.0995x over previous
//
#include <hip/hip_runtime.h>
#include <math.h>

#define Bn 8
#define Nn 8192
#define Dn 64
#define Sn 2048
#define NS 32

// DPP helper: returns permuted src (untouched lanes keep 'old' = v).
#define DPP_STEP(v, ctrl, rmask)                                               \
    __builtin_amdgcn_update_dpp((v), (v), (ctrl), (rmask), 0xf, false)

// ---------------------------------------------------------------------------
// FPS: one block per batch, 512 threads, 16 points/thread (chunked so lane
// order == index order). One barrier/iter (double-buffered candidates).
// Wave argmax via DPP (VALU pipe) instead of ds_bpermute shuffles.
// Bit-exact vs numpy: contract off, ((dx2+dy2)+dz2), strict > = first max,
// cross-wave tie-break via (valbits<<32)|(8191-idx) u64 max.
// ---------------------------------------------------------------------------
__global__ __launch_bounds__(512)
void fps_kernel(const float* __restrict__ xyz, float* __restrict__ newxyz)
{
#pragma clang fp contract(off)
    const int b = blockIdx.x;
    const int tid = threadIdx.x;
    const int lane = tid & 63;
    const int wv = tid >> 6;                    // 0..7
    __shared__ float4 lxyz[Nn];                 // 128 KB packed coords
    __shared__ int lfar[Sn];                    // 8 KB
    __shared__ unsigned long long cand[2][8];
    const float* xb = xyz + (size_t)b * 3 * Nn;
    float px[16], py[16], pz[16], pd[16];
    const int base = tid * 16;
#pragma unroll
    for (int i4 = 0; i4 < 16; i4 += 4) {
        float4 vx = *(const float4*)(xb + base + i4);
        float4 vy = *(const float4*)(xb + Nn + base + i4);
        float4 vz = *(const float4*)(xb + 2 * Nn + base + i4);
        px[i4] = vx.x; px[i4 + 1] = vx.y; px[i4 + 2] = vx.z; px[i4 + 3] = vx.w;
        py[i4] = vy.x; py[i4 + 1] = vy.y; py[i4 + 2] = vy.z; py[i4 + 3] = vy.w;
        pz[i4] = vz.x; pz[i4 + 1] = vz.y; pz[i4 + 2] = vz.z; pz[i4 + 3] = vz.w;
    }
#pragma unroll
    for (int i = 0; i < 16; ++i) {
        lxyz[base + i] = make_float4(px[i], py[i], pz[i], 0.0f);
        pd[i] = 1e10f;
    }
    if (tid == 0) lfar[0] = 0;
    __syncthreads();
    int far = 0;
    for (int t = 1; t < Sn; ++t) {
        float4 cen = lxyz[far];                 // uniform broadcast ds_read_b128
        float best = -1.0f; int bi = 0;
#pragma unroll
        for (int i = 0; i < 16; ++i) {
            float dx = px[i] - cen.x;
            float dy = py[i] - cen.y;
            float dz = pz[i] - cen.z;
            float d = (dx * dx + dy * dy) + dz * dz;
            float nd = fminf(pd[i], d);
            pd[i] = nd;
            if (nd > best) { best = nd; bi = i; }   // strict > => first (smallest i)
        }
        // ---- wave max via DPP (VALU pipe, no LDS latency) ----
        // distances are >= 0 so 'best' >= 0; untouched lanes keep own value.
        int vb = __float_as_int(best);
        { int s_;
          s_ = DPP_STEP(vb, 0x111, 0xf); vb = __float_as_int(fmaxf(__int_as_float(vb), __int_as_float(s_)));  // row_shr:1
          s_ = DPP_STEP(vb, 0x112, 0xf); vb = __float_as_int(fmaxf(__int_as_float(vb), __int_as_float(s_)));  // row_shr:2
          s_ = DPP_STEP(vb, 0x114, 0xf); vb = __float_as_int(fmaxf(__int_as_float(vb), __int_as_float(s_)));  // row_shr:4
          s_ = DPP_STEP(vb, 0x118, 0xf); vb = __float_as_int(fmaxf(__int_as_float(vb), __int_as_float(s_)));  // row_shr:8
          s_ = DPP_STEP(vb, 0x142, 0xa); vb = __float_as_int(fmaxf(__int_as_float(vb), __int_as_float(s_)));  // row_bcast:15 -> rows 1,3
          s_ = DPP_STEP(vb, 0x143, 0xc); vb = __float_as_int(fmaxf(__int_as_float(vb), __int_as_float(s_)));  // row_bcast:31 -> rows 2,3
        }
        const int smax = __builtin_amdgcn_readlane(vb, 63);   // wave-uniform max bits
        const float wmaxf = __int_as_float(smax);
        unsigned long long m = __ballot(best == wmaxf);
        int fl = (int)__ffsll((long long)m) - 1;              // lowest lane = smallest chunk
        int gidx = __builtin_amdgcn_readlane(base + bi, fl);  // wave-uniform
        unsigned long long key = ((unsigned long long)(unsigned)smax << 32)
                               | (unsigned)(8191 - gidx);
        if (lane == 0) cand[t & 1][wv] = key;
        __syncthreads();
        // every wave redundantly reduces the 8 candidates (no 2nd barrier)
        unsigned long long bc = cand[t & 1][0];
#pragma unroll
        for (int w = 1; w < 8; ++w) {
            unsigned long long cc = cand[t & 1][w];
            bc = (cc > bc) ? cc : bc;
        }
        far = 8191 - (int)(bc & 0x3FFFu);
        if (tid == 0) lfar[t] = far;
    }
    __syncthreads();
    for (int t = tid; t < Sn; t += 512) {
        float4 p = lxyz[lfar[t]];
        newxyz[(size_t)b * 3 * Sn + t]          = p.x;
        newxyz[(size_t)b * 3 * Sn + Sn + t]     = p.y;
        newxyz[(size_t)b * 3 * Sn + 2 * Sn + t] = p.z;
    }
}

// ---------------------------------------------------------------------------
// Ball query: one wave per (b,s). Scan points in index order, first NS hits;
// pad with first hit. Bit-exact distance + threshold (float)(0.4*0.4).
// ---------------------------------------------------------------------------
__global__ __launch_bounds__(256)
void ballq_kernel(const float* __restrict__ xyz, const float* __restrict__ newxyz,
                  int* __restrict__ idxbuf)
{
#pragma clang fp contract(off)
    const int gw = (blockIdx.x * 256 + threadIdx.x) >> 6;  // global wave id = b*Sn + s
    const int lane = threadIdx.x & 63;
    const int b = gw >> 11;
    const int s = gw & (Sn - 1);
    const float* xb = xyz + (size_t)b * 3 * Nn;
    const float cx = newxyz[(size_t)b * 3 * Sn + s];
    const float cy = newxyz[(size_t)b * 3 * Sn + Sn + s];
    const float cz = newxyz[(size_t)b * 3 * Sn + 2 * Sn + s];
    int* op = idxbuf + (size_t)gw * NS;
    const float R2 = (float)(0.4 * 0.4);   // 0.15999999642f, matches numpy
    int cnt = 0, first = -1;
    for (int base = 0; base < Nn && cnt < NS; base += 64) {
        int j = base + lane;
        float dx = cx - xb[j];
        float dy = cy - xb[Nn + j];
        float dz = cz - xb[2 * Nn + j];
        float d = (dx * dx + dy * dy) + dz * dz;
        bool hit = d <= R2;
        unsigned long long m = __ballot(hit);
        if (hit) {
            int pos = cnt + __popcll(m & ((1ull << lane) - 1ull));
            if (pos < NS) op[pos] = j;
        }
        if (first < 0 && m != 0ull) first = base + (int)__ffsll((long long)m) - 1;
        cnt += (int)__popcll(m);
    }
    for (int p = cnt + lane; p < NS; p += 64) op[p] = first;  // pad with first hit
}

// ---------------------------------------------------------------------------
// Fold BN (eval) into conv weights: wf = w*scale_c, bias = b - m*scale_c.
// ---------------------------------------------------------------------------
__global__ void prep_kernel(const float* __restrict__ w0, const float* __restrict__ w1,
                            const float* __restrict__ w2,
                            const float* __restrict__ g0, const float* __restrict__ b0,
                            const float* __restrict__ m0, const float* __restrict__ v0,
                            const float* __restrict__ g1, const float* __restrict__ b1,
                            const float* __restrict__ m1, const float* __restrict__ v1,
                            const float* __restrict__ g2, const float* __restrict__ b2,
                            const float* __restrict__ m2, const float* __restrict__ v2,
                            float* __restrict__ wb)
{
    int t = blockIdx.x * blockDim.x + threadIdx.x;
    if (t < 64 * 67) { int c = t / 67; float sc = g0[c] / sqrtf(v0[c] + 1e-5f); wb[t] = w0[t] * sc; }
    if (t < 64)      { float sc = g0[t] / sqrtf(v0[t] + 1e-5f); wb[4288 + t] = b0[t] - m0[t] * sc; }
    if (t < 64 * 64) { int c = t / 64; float sc = g1[c] / sqrtf(v1[c] + 1e-5f); wb[4352 + t] = w1[t] * sc; }
    if (t < 64)      { float sc = g1[t] / sqrtf(v1[t] + 1e-5f); wb[8448 + t] = b1[t] - m1[t] * sc; }
    if (t < 128 * 64){ int c = t / 64; float sc = g2[c] / sqrtf(v2[c] + 1e-5f); wb[8512 + t] = w2[t] * sc; }
    if (t < 128)     { float sc = g2[t] / sqrtf(v2[t] + 1e-5f); wb[16704 + t] = b2[t] - m2[t] * sc; }
}

// ---------------------------------------------------------------------------
// Fused group + MLP(67->64->64->128) + maxpool over 32 samples.
// One thread per (b,s,k) sample; weights via uniform loads; max-reduce
// across the 32 lanes of each half-wave.
// ---------------------------------------------------------------------------
__global__ __launch_bounds__(256)
void mlp_kernel(const float* __restrict__ xyz, const float* __restrict__ points,
                const float* __restrict__ newxyz, const int* __restrict__ idxbuf,
                const float* __restrict__ wb, float* __restrict__ outp)
{
    const int gid = blockIdx.x * 256 + threadIdx.x;
    const int k  = gid & (NS - 1);
    const int bs = gid >> 5;             // b*Sn + s
    const int s  = bs & (Sn - 1);
    const int b  = bs >> 11;
    const int j  = idxbuf[(size_t)bs * NS + k];
    const float* xb = xyz + (size_t)b * 3 * Nn;
    float x0, x1, x2;
    {
#pragma clang fp contract(off)
        x0 = xb[j]          - newxyz[(size_t)b * 3 * Sn + s];
        x1 = xb[Nn + j]     - newxyz[(size_t)b * 3 * Sn + Sn + s];
        x2 = xb[2 * Nn + j] - newxyz[(size_t)b * 3 * Sn + 2 * Sn + s];
    }
    const float* pb = points + (size_t)b * Dn * Nn + j;
    float xf[64];
#pragma unroll
    for (int d = 0; d < 64; ++d) xf[d] = pb[(size_t)d * Nn];

    // layer 0: 67 -> 64
    const float* w0  = wb;
    const float* bb0 = wb + 64 * 67;
    float h0[64];
#pragma unroll 2
    for (int c = 0; c < 64; ++c) {
        const float* wr = w0 + c * 67;
        float a0 = fmaf(wr[0], x0, bb0[c]);
        float a1 = wr[1] * x1;
        float a2 = wr[2] * x2;
        float a3 = 0.0f;
#pragma unroll
        for (int d = 0; d < 64; d += 4) {
            a0 = fmaf(wr[3 + d], xf[d],     a0);
            a1 = fmaf(wr[4 + d], xf[d + 1], a1);
            a2 = fmaf(wr[5 + d], xf[d + 2], a2);
            a3 = fmaf(wr[6 + d], xf[d + 3], a3);
        }
        h0[c] = fmaxf((a0 + a1) + (a2 + a3), 0.0f);
    }
    // layer 1: 64 -> 64
    const float* w1  = wb + 4352;
    const float* bb1 = wb + 8448;
    float h1[64];
#pragma unroll 2
    for (int c = 0; c < 64; ++c) {
        const float* wr = w1 + c * 64;
        float a0 = bb1[c], a1 = 0.f, a2 = 0.f, a3 = 0.f;
#pragma unroll
        for (int d = 0; d < 64; d += 4) {
            a0 = fmaf(wr[d],     h0[d],     a0);
            a1 = fmaf(wr[d + 1], h0[d + 1], a1);
            a2 = fmaf(wr[d + 2], h0[d + 2], a2);
            a3 = fmaf(wr[d + 3], h0[d + 3], a3);
        }
        h1[c] = fmaxf((a0 + a1) + (a2 + a3), 0.0f);
    }
    // layer 2: 64 -> 128, fused max over k (lanes 0..31 / 32..63 groups)
    const float* w2  = wb + 8512;
    const float* bb2 = wb + 16704;
    float* ob = outp + ((size_t)b * 128) * Sn + s;
#pragma unroll 2
    for (int c = 0; c < 128; ++c) {
        const float* wr = w2 + c * 64;
        float a0 = bb2[c], a1 = 0.f, a2 = 0.f, a3 = 0.f;
#pragma unroll
        for (int d = 0; d < 64; d += 4) {
            a0 = fmaf(wr[d],     h1[d],     a0);
            a1 = fmaf(wr[d + 1], h1[d + 1], a1);
            a2 = fmaf(wr[d + 2], h1[d + 2], a2);
            a3 = fmaf(wr[d + 3], h1[d + 3], a3);
        }
        float acc = fmaxf((a0 + a1) + (a2 + a3), 0.0f);
#pragma unroll
        for (int off = 1; off < 32; off <<= 1) acc = fmaxf(acc, __shfl_xor(acc, off));
        if (k == 0) ob[(size_t)c * Sn] = acc;
    }
}

extern "C" void kernel_launch(void* const* d_in, const int* in_sizes, int n_in,
                              void* d_out, int out_size, void* d_ws, size_t ws_size,
                              hipStream_t stream)
{
    const float* xyz    = (const float*)d_in[0];
    const float* points = (const float*)d_in[1];
    const float* w0 = (const float*)d_in[2];
    const float* w1 = (const float*)d_in[3];
    const float* w2 = (const float*)d_in[4];
    const float* g0 = (const float*)d_in[5];
    const float* b0 = (const float*)d_in[6];
    const float* m0 = (const float*)d_in[7];
    const float* v0 = (const float*)d_in[8];
    const float* g1 = (const float*)d_in[9];
    const float* b1 = (const float*)d_in[10];
    const float* m1 = (const float*)d_in[11];
    const float* v1 = (const float*)d_in[12];
    const float* g2 = (const float*)d_in[13];
    const float* b2 = (const float*)d_in[14];
    const float* m2 = (const float*)d_in[15];
    const float* v2 = (const float*)d_in[16];

    float* out = (float*)d_out;                       // new_xyz [8,3,2048] then new_points [8,128,2048]
    float* wb  = (float*)d_ws;                        // 16832 floats of folded weights
    int*   idx = (int*)((char*)d_ws + 128 * 1024);    // [8,2048,32] int

    prep_kernel<<<32, 256, 0, stream>>>(w0, w1, w2, g0, b0, m0, v0,
                                        g1, b1, m1, v1, g2, b2, m2, v2, wb);
    fps_kernel<<<Bn, 512, 0, stream>>>(xyz, out);
    ballq_kernel<<<(Bn * Sn * 64) / 256, 256, 0, stream>>>(xyz, out, idx);
    mlp_kernel<<<(Bn * Sn * NS) / 256, 256, 0, stream>>>(xyz, points, out, idx, wb,
                                                         out + Bn * 3 * Sn);
}

// Round 4
// 2552.151 us; speedup vs baseline: 1.7049x; 1.0992x over previous
//
#include <hip/hip_runtime.h>
#include <math.h>

#define Bn 8
#define Nn 8192
#define Dn 64
#define Sn 2048
#define NS 32

typedef float f2 __attribute__((ext_vector_type(2)));
typedef unsigned long long u64;

// DPP helper: returns permuted src (untouched lanes keep own value).
#define DPP_STEP(v, ctrl, rmask)                                               \
    __builtin_amdgcn_update_dpp((v), (v), (ctrl), (rmask), 0xf, false)

// ---------------------------------------------------------------------------
// FPS: one block per batch, 256 threads, 32 points/thread as 16 float2 pairs
// (chunked so lane order == index order). Distance math on ext_vector f2 ->
// v_pk_add_f32/v_pk_mul_f32 (2 pts/inst). One barrier/iter; winning wave
// publishes (u64 key, centroid xyz) together so the next iteration needs no
// dependent lxyz[far] read. newxyz written directly per iteration.
// Bit-exact vs numpy: contract off, ((dx2+dy2)+dz2), strict > = first max,
// cross-wave tie-break via (valbits<<32)|(8191-idx) u64 max.
// ---------------------------------------------------------------------------
__global__ __launch_bounds__(256)
void fps_kernel(const float* __restrict__ xyz, float* __restrict__ newxyz)
{
#pragma clang fp contract(off)
    const int b = blockIdx.x;
    const int tid = threadIdx.x;
    const int lane = tid & 63;
    const int wv = tid >> 6;                    // 0..3
    __shared__ float4 lxyz[Nn];                 // 128 KB packed coords
    __shared__ u64    ckey[2][4];
    __shared__ float4 cxyz[2][4];
    const float* xb = xyz + (size_t)b * 3 * Nn;
    f2 px[16], py[16], pz[16], pd[16];
    const int base = tid * 32;
#pragma unroll
    for (int q = 0; q < 8; ++q) {
        float4 vx = *(const float4*)(xb + base + 4 * q);
        float4 vy = *(const float4*)(xb + Nn + base + 4 * q);
        float4 vz = *(const float4*)(xb + 2 * Nn + base + 4 * q);
        px[2 * q]     = (f2){vx.x, vx.y};  px[2 * q + 1] = (f2){vx.z, vx.w};
        py[2 * q]     = (f2){vy.x, vy.y};  py[2 * q + 1] = (f2){vy.z, vy.w};
        pz[2 * q]     = (f2){vz.x, vz.y};  pz[2 * q + 1] = (f2){vz.z, vz.w};
        pd[2 * q]     = (f2){1e10f, 1e10f};
        pd[2 * q + 1] = (f2){1e10f, 1e10f};
        lxyz[base + 4 * q + 0] = make_float4(vx.x, vy.x, vz.x, 0.f);
        lxyz[base + 4 * q + 1] = make_float4(vx.y, vy.y, vz.y, 0.f);
        lxyz[base + 4 * q + 2] = make_float4(vx.z, vy.z, vz.z, 0.f);
        lxyz[base + 4 * q + 3] = make_float4(vx.w, vy.w, vz.w, 0.f);
    }
    // centroid 0 = point 0
    float cx = xb[0], cy = xb[Nn], cz = xb[2 * Nn];
    if (tid == 0) {
        newxyz[(size_t)b * 3 * Sn + 0]      = cx;
        newxyz[(size_t)b * 3 * Sn + Sn]     = cy;
        newxyz[(size_t)b * 3 * Sn + 2 * Sn] = cz;
    }
    __syncthreads();

    for (int t = 1; t < Sn; ++t) {
        f2 c0 = {cx, cx}, c1 = {cy, cy}, c2 = {cz, cz};
        float best = -1.0f; int gi = 0;
#pragma unroll
        for (int i = 0; i < 16; ++i) {
            f2 dx = px[i] - c0;
            f2 dy = py[i] - c1;
            f2 dz = pz[i] - c2;
            f2 s0 = dx * dx;
            f2 s1 = dy * dy;
            f2 s2 = dz * dz;
            f2 d  = (s0 + s1) + s2;            // ((dx2+dy2)+dz2), per component
            f2 nd;
            nd.x = fminf(pd[i].x, d.x);
            nd.y = fminf(pd[i].y, d.y);
            pd[i] = nd;
            if (nd.x > best) { best = nd.x; gi = base + 2 * i; }      // strict >
            if (nd.y > best) { best = nd.y; gi = base + 2 * i + 1; }  // => first
        }
        // wave value-max via DPP (VALU pipe)
        int vb = __float_as_int(best);                   // dists >= 0: bit-monotone
        { int s_;
          s_ = DPP_STEP(vb, 0x111, 0xf); vb = __float_as_int(fmaxf(__int_as_float(vb), __int_as_float(s_)));  // row_shr:1
          s_ = DPP_STEP(vb, 0x112, 0xf); vb = __float_as_int(fmaxf(__int_as_float(vb), __int_as_float(s_)));  // row_shr:2
          s_ = DPP_STEP(vb, 0x114, 0xf); vb = __float_as_int(fmaxf(__int_as_float(vb), __int_as_float(s_)));  // row_shr:4
          s_ = DPP_STEP(vb, 0x118, 0xf); vb = __float_as_int(fmaxf(__int_as_float(vb), __int_as_float(s_)));  // row_shr:8
          s_ = DPP_STEP(vb, 0x142, 0xa); vb = __float_as_int(fmaxf(__int_as_float(vb), __int_as_float(s_)));  // row_bcast:15
          s_ = DPP_STEP(vb, 0x143, 0xc); vb = __float_as_int(fmaxf(__int_as_float(vb), __int_as_float(s_)));  // row_bcast:31
        }
        const int smax = __builtin_amdgcn_readlane(vb, 63);
        const float wmaxf = __int_as_float(smax);
        u64 m = __ballot(best == wmaxf);
        int fl = (int)__ffsll((long long)m) - 1;         // lowest lane = smallest idx
        int gw_ = __builtin_amdgcn_readlane(gi, fl);
        if (lane == 0) {                                 // publish key + coords
            float4 wc = lxyz[gw_];
            ckey[t & 1][wv] = ((u64)(unsigned)smax << 32) | (unsigned)(8191 - gw_);
            cxyz[t & 1][wv] = wc;
        }
        __syncthreads();
        u64 k0 = ckey[t & 1][0], k1 = ckey[t & 1][1];
        u64 k2 = ckey[t & 1][2], k3 = ckey[t & 1][3];
        float4 q0 = cxyz[t & 1][0], q1 = cxyz[t & 1][1];
        float4 q2 = cxyz[t & 1][2], q3 = cxyz[t & 1][3];
        if (k1 > k0) { k0 = k1; q0 = q1; }               // larger key wins;
        if (k3 > k2) { k2 = k3; q2 = q3; }               // tie -> smaller idx
        if (k2 > k0) { k0 = k2; q0 = q2; }
        cx = q0.x; cy = q0.y; cz = q0.z;
        if (tid == 0) {
            newxyz[(size_t)b * 3 * Sn + t]          = cx;
            newxyz[(size_t)b * 3 * Sn + Sn + t]     = cy;
            newxyz[(size_t)b * 3 * Sn + 2 * Sn + t] = cz;
        }
    }
}

// ---------------------------------------------------------------------------
// Ball query: one wave per (b,s). Scan points in index order, first NS hits;
// pad with first hit. Bit-exact distance + threshold (float)(0.4*0.4).
// ---------------------------------------------------------------------------
__global__ __launch_bounds__(256)
void ballq_kernel(const float* __restrict__ xyz, const float* __restrict__ newxyz,
                  int* __restrict__ idxbuf)
{
#pragma clang fp contract(off)
    const int gw = (blockIdx.x * 256 + threadIdx.x) >> 6;  // global wave id = b*Sn + s
    const int lane = threadIdx.x & 63;
    const int b = gw >> 11;
    const int s = gw & (Sn - 1);
    const float* xb = xyz + (size_t)b * 3 * Nn;
    const float cx = newxyz[(size_t)b * 3 * Sn + s];
    const float cy = newxyz[(size_t)b * 3 * Sn + Sn + s];
    const float cz = newxyz[(size_t)b * 3 * Sn + 2 * Sn + s];
    int* op = idxbuf + (size_t)gw * NS;
    const float R2 = (float)(0.4 * 0.4);   // 0.15999999642f, matches numpy
    int cnt = 0, first = -1;
    for (int base = 0; base < Nn && cnt < NS; base += 64) {
        int j = base + lane;
        float dx = cx - xb[j];
        float dy = cy - xb[Nn + j];
        float dz = cz - xb[2 * Nn + j];
        float d = (dx * dx + dy * dy) + dz * dz;
        bool hit = d <= R2;
        unsigned long long m = __ballot(hit);
        if (hit) {
            int pos = cnt + __popcll(m & ((1ull << lane) - 1ull));
            if (pos < NS) op[pos] = j;
        }
        if (first < 0 && m != 0ull) first = base + (int)__ffsll((long long)m) - 1;
        cnt += (int)__popcll(m);
    }
    for (int p = cnt + lane; p < NS; p += 64) op[p] = first;  // pad with first hit
}

// ---------------------------------------------------------------------------
// Fold BN (eval) into conv weights: wf = w*scale_c, bias = b - m*scale_c.
// ---------------------------------------------------------------------------
__global__ void prep_kernel(const float* __restrict__ w0, const float* __restrict__ w1,
                            const float* __restrict__ w2,
                            const float* __restrict__ g0, const float* __restrict__ b0,
                            const float* __restrict__ m0, const float* __restrict__ v0,
                            const float* __restrict__ g1, const float* __restrict__ b1,
                            const float* __restrict__ m1, const float* __restrict__ v1,
                            const float* __restrict__ g2, const float* __restrict__ b2,
                            const float* __restrict__ m2, const float* __restrict__ v2,
                            float* __restrict__ wb)
{
    int t = blockIdx.x * blockDim.x + threadIdx.x;
    if (t < 64 * 67) { int c = t / 67; float sc = g0[c] / sqrtf(v0[c] + 1e-5f); wb[t] = w0[t] * sc; }
    if (t < 64)      { float sc = g0[t] / sqrtf(v0[t] + 1e-5f); wb[4288 + t] = b0[t] - m0[t] * sc; }
    if (t < 64 * 64) { int c = t / 64; float sc = g1[c] / sqrtf(v1[c] + 1e-5f); wb[4352 + t] = w1[t] * sc; }
    if (t < 64)      { float sc = g1[t] / sqrtf(v1[t] + 1e-5f); wb[8448 + t] = b1[t] - m1[t] * sc; }
    if (t < 128 * 64){ int c = t / 64; float sc = g2[c] / sqrtf(v2[c] + 1e-5f); wb[8512 + t] = w2[t] * sc; }
    if (t < 128)     { float sc = g2[t] / sqrtf(v2[t] + 1e-5f); wb[16704 + t] = b2[t] - m2[t] * sc; }
}

// ---------------------------------------------------------------------------
// Fused group + MLP(67->64->64->128) + maxpool over 32 samples.
// One thread per (b,s,k) sample; weights via uniform loads; max-reduce
// across the 32 lanes of each half-wave.
// ---------------------------------------------------------------------------
__global__ __launch_bounds__(256)
void mlp_kernel(const float* __restrict__ xyz, const float* __restrict__ points,
                const float* __restrict__ newxyz, const int* __restrict__ idxbuf,
                const float* __restrict__ wb, float* __restrict__ outp)
{
    const int gid = blockIdx.x * 256 + threadIdx.x;
    const int k  = gid & (NS - 1);
    const int bs = gid >> 5;             // b*Sn + s
    const int s  = bs & (Sn - 1);
    const int b  = bs >> 11;
    const int j  = idxbuf[(size_t)bs * NS + k];
    const float* xb = xyz + (size_t)b * 3 * Nn;
    float x0, x1, x2;
    {
#pragma clang fp contract(off)
        x0 = xb[j]          - newxyz[(size_t)b * 3 * Sn + s];
        x1 = xb[Nn + j]     - newxyz[(size_t)b * 3 * Sn + Sn + s];
        x2 = xb[2 * Nn + j] - newxyz[(size_t)b * 3 * Sn + 2 * Sn + s];
    }
    const float* pb = points + (size_t)b * Dn * Nn + j;
    float xf[64];
#pragma unroll
    for (int d = 0; d < 64; ++d) xf[d] = pb[(size_t)d * Nn];

    // layer 0: 67 -> 64
    const float* w0  = wb;
    const float* bb0 = wb + 64 * 67;
    float h0[64];
#pragma unroll 2
    for (int c = 0; c < 64; ++c) {
        const float* wr = w0 + c * 67;
        float a0 = fmaf(wr[0], x0, bb0[c]);
        float a1 = wr[1] * x1;
        float a2 = wr[2] * x2;
        float a3 = 0.0f;
#pragma unroll
        for (int d = 0; d < 64; d += 4) {
            a0 = fmaf(wr[3 + d], xf[d],     a0);
            a1 = fmaf(wr[4 + d], xf[d + 1], a1);
            a2 = fmaf(wr[5 + d], xf[d + 2], a2);
            a3 = fmaf(wr[6 + d], xf[d + 3], a3);
        }
        h0[c] = fmaxf((a0 + a1) + (a2 + a3), 0.0f);
    }
    // layer 1: 64 -> 64
    const float* w1  = wb + 4352;
    const float* bb1 = wb + 8448;
    float h1[64];
#pragma unroll 2
    for (int c = 0; c < 64; ++c) {
        const float* wr = w1 + c * 64;
        float a0 = bb1[c], a1 = 0.f, a2 = 0.f, a3 = 0.f;
#pragma unroll
        for (int d = 0; d < 64; d += 4) {
            a0 = fmaf(wr[d],     h0[d],     a0);
            a1 = fmaf(wr[d + 1], h0[d + 1], a1);
            a2 = fmaf(wr[d + 2], h0[d + 2], a2);
            a3 = fmaf(wr[d + 3], h0[d + 3], a3);
        }
        h1[c] = fmaxf((a0 + a1) + (a2 + a3), 0.0f);
    }
    // layer 2: 64 -> 128, fused max over k (lanes 0..31 / 32..63 groups)
    const float* w2  = wb + 8512;
    const float* bb2 = wb + 16704;
    float* ob = outp + ((size_t)b * 128) * Sn + s;
#pragma unroll 2
    for (int c = 0; c < 128; ++c) {
        const float* wr = w2 + c * 64;
        float a0 = bb2[c], a1 = 0.f, a2 = 0.f, a3 = 0.f;
#pragma unroll
        for (int d = 0; d < 64; d += 4) {
            a0 = fmaf(wr[d],     h1[d],     a0);
            a1 = fmaf(wr[d + 1], h1[d + 1], a1);
            a2 = fmaf(wr[d + 2], h1[d + 2], a2);
            a3 = fmaf(wr[d + 3], h1[d + 3], a3);
        }
        float acc = fmaxf((a0 + a1) + (a2 + a3), 0.0f);
#pragma unroll
        for (int off = 1; off < 32; off <<= 1) acc = fmaxf(acc, __shfl_xor(acc, off));
        if (k == 0) ob[(size_t)c * Sn] = acc;
    }
}

extern "C" void kernel_launch(void* const* d_in, const int* in_sizes, int n_in,
                              void* d_out, int out_size, void* d_ws, size_t ws_size,
                              hipStream_t stream)
{
    const float* xyz    = (const float*)d_in[0];
    const float* points = (const float*)d_in[1];
    const float* w0 = (const float*)d_in[2];
    const float* w1 = (const float*)d_in[3];
    const float* w2 = (const float*)d_in[4];
    const float* g0 = (const float*)d_in[5];
    const float* b0 = (const float*)d_in[6];
    const float* m0 = (const float*)d_in[7];
    const float* v0 = (const float*)d_in[8];
    const float* g1 = (const float*)d_in[9];
    const float* b1 = (const float*)d_in[10];
    const float* m1 = (const float*)d_in[11];
    const float* v1 = (const float*)d_in[12];
    const float* g2 = (const float*)d_in[13];
    const float* b2 = (const float*)d_in[14];
    const float* m2 = (const float*)d_in[15];
    const float* v2 = (const float*)d_in[16];

    float* out = (float*)d_out;                       // new_xyz [8,3,2048] then new_points [8,128,2048]
    float* wb  = (float*)d_ws;                        // 16832 floats of folded weights
    int*   idx = (int*)((char*)d_ws + 128 * 1024);    // [8,2048,32] int

    prep_kernel<<<32, 256, 0, stream>>>(w0, w1, w2, g0, b0, m0, v0,
                                        g1, b1, m1, v1, g2, b2, m2, v2, wb);
    fps_kernel<<<Bn, 256, 0, stream>>>(xyz, out);
    ballq_kernel<<<(Bn * Sn * 64) / 256, 256, 0, stream>>>(xyz, out, idx);
    mlp_kernel<<<(Bn * Sn * NS) / 256, 256, 0, stream>>>(xyz, points, out, idx, wb,
                                                         out + Bn * 3 * Sn);
}

// Round 5
// 2330.727 us; speedup vs baseline: 1.8668x; 1.0950x over previous
//
#include <hip/hip_runtime.h>
#include <math.h>

#define Bn 8
#define Nn 8192
#define Dn 64
#define Sn 2048
#define NS 32
#define NCONS 240

typedef float f2 __attribute__((ext_vector_type(2)));
typedef unsigned long long u64;

// DPP helper: returns permuted src (untouched lanes keep own value).
#define DPP_STEP(v, ctrl, rmask)                                               \
    __builtin_amdgcn_update_dpp((v), (v), (ctrl), (rmask), 0xf, false)

// Device-scope (AGENT) relaxed atomics: sc1 write-through/read-through the
// coherent point -> safe across non-coherent per-XCD L2s.
#define ATOMIC_ST(p, v) __hip_atomic_store((p), (v), __ATOMIC_RELAXED, __HIP_MEMORY_SCOPE_AGENT)
#define ATOMIC_LD(p)    __hip_atomic_load((p), __ATOMIC_RELAXED, __HIP_MEMORY_SCOPE_AGENT)

// ---------------------------------------------------------------------------
// Fused producer/consumer kernel.
//  blocks 0..7     : FPS for batch b (verified R3 code) + progressive publish
//  blocks 8..247   : consumers; block c handles samples t = c, c+240, ...
// Co-residency: 132KB LDS -> 1 block/CU; 248 blocks <= 256 CUs -> all
// resident at launch regardless of dispatch order -> no spin deadlock.
// Publish protocol: coords via relaxed AGENT atomics (coherent point);
// prog[b] = t-3 published at iter t (4-iter ~3.3us lag >> store latency)
// so consumers never observe a published-but-incomplete coordinate.
// Poisoned prog (0xAAAAAAAA) is negative -> consumers spin until written.
// ---------------------------------------------------------------------------
__global__ __launch_bounds__(256)
void fused_kernel(const float* __restrict__ xyz, const float* __restrict__ points,
                  const float* __restrict__ wb, float* __restrict__ newxyz_f,
                  float* __restrict__ outp, int* __restrict__ prog)
{
#pragma clang fp contract(off)
    __shared__ float4 lxyz[Nn];                 // 128 KB (fps role)
    __shared__ u64    ckey[2][4];
    __shared__ float4 cxyz[2][4];
    __shared__ int    lidx[4][2][NS];           // 1 KB (consumer role)
    const int tid = threadIdx.x;
    const int lane = tid & 63;
    int* newxyz_i = (int*)newxyz_f;

    if (blockIdx.x < Bn) {
        // ===================== producer: FPS =====================
        const int b = blockIdx.x;
        const int wv = tid >> 6;                // 0..3
        const float* xb = xyz + (size_t)b * 3 * Nn;
        f2 px[16], py[16], pz[16], pd[16];
        const int base = tid * 32;
#pragma unroll
        for (int q = 0; q < 8; ++q) {
            float4 vx = *(const float4*)(xb + base + 4 * q);
            float4 vy = *(const float4*)(xb + Nn + base + 4 * q);
            float4 vz = *(const float4*)(xb + 2 * Nn + base + 4 * q);
            px[2 * q]     = (f2){vx.x, vx.y};  px[2 * q + 1] = (f2){vx.z, vx.w};
            py[2 * q]     = (f2){vy.x, vy.y};  py[2 * q + 1] = (f2){vy.z, vy.w};
            pz[2 * q]     = (f2){vz.x, vz.y};  pz[2 * q + 1] = (f2){vz.z, vz.w};
            pd[2 * q]     = (f2){1e10f, 1e10f};
            pd[2 * q + 1] = (f2){1e10f, 1e10f};
            lxyz[base + 4 * q + 0] = make_float4(vx.x, vy.x, vz.x, 0.f);
            lxyz[base + 4 * q + 1] = make_float4(vx.y, vy.y, vz.y, 0.f);
            lxyz[base + 4 * q + 2] = make_float4(vx.z, vy.z, vz.z, 0.f);
            lxyz[base + 4 * q + 3] = make_float4(vx.w, vy.w, vz.w, 0.f);
        }
        float cx = xb[0], cy = xb[Nn], cz = xb[2 * Nn];
        const size_t nb0 = (size_t)b * 3 * Sn;
        if (tid == 0) {
            ATOMIC_ST(newxyz_i + nb0,          __float_as_int(cx));
            ATOMIC_ST(newxyz_i + nb0 + Sn,     __float_as_int(cy));
            ATOMIC_ST(newxyz_i + nb0 + 2 * Sn, __float_as_int(cz));
        }
        __syncthreads();

        for (int t = 1; t < Sn; ++t) {
            f2 c0 = {cx, cx}, c1 = {cy, cy}, c2 = {cz, cz};
            float best = -1.0f; int gi = 0;
#pragma unroll
            for (int i = 0; i < 16; ++i) {
                f2 dx = px[i] - c0;
                f2 dy = py[i] - c1;
                f2 dz = pz[i] - c2;
                f2 s0 = dx * dx;
                f2 s1 = dy * dy;
                f2 s2 = dz * dz;
                f2 d  = (s0 + s1) + s2;        // ((dx2+dy2)+dz2) per component
                f2 nd;
                nd.x = fminf(pd[i].x, d.x);
                nd.y = fminf(pd[i].y, d.y);
                pd[i] = nd;
                if (nd.x > best) { best = nd.x; gi = base + 2 * i; }      // strict >
                if (nd.y > best) { best = nd.y; gi = base + 2 * i + 1; }  // => first
            }
            // wave value-max via DPP (VALU pipe)
            int vb = __float_as_int(best);     // dists >= 0: bit-monotone
            { int s_;
              s_ = DPP_STEP(vb, 0x111, 0xf); vb = __float_as_int(fmaxf(__int_as_float(vb), __int_as_float(s_)));
              s_ = DPP_STEP(vb, 0x112, 0xf); vb = __float_as_int(fmaxf(__int_as_float(vb), __int_as_float(s_)));
              s_ = DPP_STEP(vb, 0x114, 0xf); vb = __float_as_int(fmaxf(__int_as_float(vb), __int_as_float(s_)));
              s_ = DPP_STEP(vb, 0x118, 0xf); vb = __float_as_int(fmaxf(__int_as_float(vb), __int_as_float(s_)));
              s_ = DPP_STEP(vb, 0x142, 0xa); vb = __float_as_int(fmaxf(__int_as_float(vb), __int_as_float(s_)));
              s_ = DPP_STEP(vb, 0x143, 0xc); vb = __float_as_int(fmaxf(__int_as_float(vb), __int_as_float(s_)));
            }
            const int smax = __builtin_amdgcn_readlane(vb, 63);
            const float wmaxf = __int_as_float(smax);
            u64 m = __ballot(best == wmaxf);
            int fl = (int)__ffsll((long long)m) - 1;     // lowest lane = smallest idx
            int gw_ = __builtin_amdgcn_readlane(gi, fl);
            if (lane == 0) {                             // publish key + coords
                float4 wc = lxyz[gw_];
                ckey[t & 1][wv] = ((u64)(unsigned)smax << 32) | (unsigned)(8191 - gw_);
                cxyz[t & 1][wv] = wc;
            }
            __syncthreads();
            u64 k0 = ckey[t & 1][0], k1 = ckey[t & 1][1];
            u64 k2 = ckey[t & 1][2], k3 = ckey[t & 1][3];
            float4 q0 = cxyz[t & 1][0], q1 = cxyz[t & 1][1];
            float4 q2 = cxyz[t & 1][2], q3 = cxyz[t & 1][3];
            if (k1 > k0) { k0 = k1; q0 = q1; }           // larger key wins;
            if (k3 > k2) { k2 = k3; q2 = q3; }           // tie -> smaller idx
            if (k2 > k0) { k0 = k2; q0 = q2; }
            cx = q0.x; cy = q0.y; cz = q0.z;
            if (tid == 0) {
                ATOMIC_ST(prog + b, t - 3);              // lagged publish (see header)
                ATOMIC_ST(newxyz_i + nb0 + t,          __float_as_int(cx));
                ATOMIC_ST(newxyz_i + nb0 + Sn + t,     __float_as_int(cy));
                ATOMIC_ST(newxyz_i + nb0 + 2 * Sn + t, __float_as_int(cz));
            }
        }
        if (tid == 0) {
            asm volatile("s_waitcnt vmcnt(0)" ::: "memory");  // drain last coord stores
            ATOMIC_ST(prog + b, Sn);
        }
    } else {
        // ===================== consumer: ballq + MLP =====================
        const int cid = blockIdx.x - Bn;
        const int w = tid >> 6;                 // wave 0..3
        const float R2 = (float)(0.4 * 0.4);    // 0.15999999642f, matches numpy
        for (int t = cid; t < Sn; t += NCONS) {
            if (tid < Bn) {
                while (ATOMIC_LD(prog + tid) < t + 1) __builtin_amdgcn_s_sleep(8);
            }
            __syncthreads();
            const int myb = 2 * w + (lane >> 5);
            const size_t nb = (size_t)myb * 3 * Sn;
            const float cxm = __int_as_float(ATOMIC_LD(newxyz_i + nb + t));
            const float cym = __int_as_float(ATOMIC_LD(newxyz_i + nb + Sn + t));
            const float czm = __int_as_float(ATOMIC_LD(newxyz_i + nb + 2 * Sn + t));
            // ---- ball query: wave handles batches 2w and 2w+1 ----
#pragma unroll
            for (int h = 0; h < 2; ++h) {
                const int bq = 2 * w + h;
                const float cx = __shfl(cxm, h * 32);
                const float cy = __shfl(cym, h * 32);
                const float cz = __shfl(czm, h * 32);
                const float* xb = xyz + (size_t)bq * 3 * Nn;
                int cnt = 0, first = -1;
                for (int bs2 = 0; bs2 < Nn && cnt < NS; bs2 += 64) {
                    int jj = bs2 + lane;
                    float dx = cx - xb[jj];
                    float dy = cy - xb[Nn + jj];
                    float dz = cz - xb[2 * Nn + jj];
                    float d = (dx * dx + dy * dy) + dz * dz;
                    bool hit = d <= R2;
                    u64 m = __ballot(hit);
                    if (hit) {
                        int pos = cnt + __popcll(m & ((1ull << lane) - 1ull));
                        if (pos < NS) lidx[w][h][pos] = jj;
                    }
                    if (first < 0 && m != 0ull) first = bs2 + (int)__ffsll((long long)m) - 1;
                    cnt += (int)__popcll(m);
                }
                for (int p = cnt + lane; p < NS; p += 64) lidx[w][h][p] = first;
            }
            // ---- MLP: lanes 0-31 -> batch 2w, lanes 32-63 -> batch 2w+1 ----
            const int k = lane & 31;
            const int j = lidx[w][lane >> 5][k];
            const float* xb2 = xyz + (size_t)myb * 3 * Nn;
            const float x0 = xb2[j]          - cxm;
            const float x1 = xb2[Nn + j]     - cym;
            const float x2 = xb2[2 * Nn + j] - czm;
            const float* pb = points + (size_t)myb * Dn * Nn + j;
            float xf[64];
#pragma unroll
            for (int d = 0; d < 64; ++d) xf[d] = pb[(size_t)d * Nn];

            const float* w0  = wb;
            const float* bb0 = wb + 64 * 67;
            float h0[64];
#pragma unroll 2
            for (int c = 0; c < 64; ++c) {
                const float* wr = w0 + c * 67;
                float a0 = fmaf(wr[0], x0, bb0[c]);
                float a1 = wr[1] * x1;
                float a2 = wr[2] * x2;
                float a3 = 0.0f;
#pragma unroll
                for (int d = 0; d < 64; d += 4) {
                    a0 = fmaf(wr[3 + d], xf[d],     a0);
                    a1 = fmaf(wr[4 + d], xf[d + 1], a1);
                    a2 = fmaf(wr[5 + d], xf[d + 2], a2);
                    a3 = fmaf(wr[6 + d], xf[d + 3], a3);
                }
                h0[c] = fmaxf((a0 + a1) + (a2 + a3), 0.0f);
            }
            const float* w1  = wb + 4352;
            const float* bb1 = wb + 8448;
            float h1[64];
#pragma unroll 2
            for (int c = 0; c < 64; ++c) {
                const float* wr = w1 + c * 64;
                float a0 = bb1[c], a1 = 0.f, a2 = 0.f, a3 = 0.f;
#pragma unroll
                for (int d = 0; d < 64; d += 4) {
                    a0 = fmaf(wr[d],     h0[d],     a0);
                    a1 = fmaf(wr[d + 1], h0[d + 1], a1);
                    a2 = fmaf(wr[d + 2], h0[d + 2], a2);
                    a3 = fmaf(wr[d + 3], h0[d + 3], a3);
                }
                h1[c] = fmaxf((a0 + a1) + (a2 + a3), 0.0f);
            }
            const float* w2  = wb + 8512;
            const float* bb2 = wb + 16704;
            float* ob = outp + ((size_t)myb * 128) * Sn + t;
#pragma unroll 2
            for (int c = 0; c < 128; ++c) {
                const float* wr = w2 + c * 64;
                float a0 = bb2[c], a1 = 0.f, a2 = 0.f, a3 = 0.f;
#pragma unroll
                for (int d = 0; d < 64; d += 4) {
                    a0 = fmaf(wr[d],     h1[d],     a0);
                    a1 = fmaf(wr[d + 1], h1[d + 1], a1);
                    a2 = fmaf(wr[d + 2], h1[d + 2], a2);
                    a3 = fmaf(wr[d + 3], h1[d + 3], a3);
                }
                float acc = fmaxf((a0 + a1) + (a2 + a3), 0.0f);
#pragma unroll
                for (int off = 1; off < 32; off <<= 1) acc = fmaxf(acc, __shfl_xor(acc, off));
                if (k == 0) ob[(size_t)c * Sn] = acc;
            }
        }
    }
}

// ---------------------------------------------------------------------------
// Fold BN (eval) into conv weights: wf = w*scale_c, bias = b - m*scale_c.
// ---------------------------------------------------------------------------
__global__ void prep_kernel(const float* __restrict__ w0, const float* __restrict__ w1,
                            const float* __restrict__ w2,
                            const float* __restrict__ g0, const float* __restrict__ b0,
                            const float* __restrict__ m0, const float* __restrict__ v0,
                            const float* __restrict__ g1, const float* __restrict__ b1,
                            const float* __restrict__ m1, const float* __restrict__ v1,
                            const float* __restrict__ g2, const float* __restrict__ b2,
                            const float* __restrict__ m2, const float* __restrict__ v2,
                            float* __restrict__ wb)
{
    int t = blockIdx.x * blockDim.x + threadIdx.x;
    if (t < 64 * 67) { int c = t / 67; float sc = g0[c] / sqrtf(v0[c] + 1e-5f); wb[t] = w0[t] * sc; }
    if (t < 64)      { float sc = g0[t] / sqrtf(v0[t] + 1e-5f); wb[4288 + t] = b0[t] - m0[t] * sc; }
    if (t < 64 * 64) { int c = t / 64; float sc = g1[c] / sqrtf(v1[c] + 1e-5f); wb[4352 + t] = w1[t] * sc; }
    if (t < 64)      { float sc = g1[t] / sqrtf(v1[t] + 1e-5f); wb[8448 + t] = b1[t] - m1[t] * sc; }
    if (t < 128 * 64){ int c = t / 64; float sc = g2[c] / sqrtf(v2[c] + 1e-5f); wb[8512 + t] = w2[t] * sc; }
    if (t < 128)     { float sc = g2[t] / sqrtf(v2[t] + 1e-5f); wb[16704 + t] = b2[t] - m2[t] * sc; }
}

extern "C" void kernel_launch(void* const* d_in, const int* in_sizes, int n_in,
                              void* d_out, int out_size, void* d_ws, size_t ws_size,
                              hipStream_t stream)
{
    const float* xyz    = (const float*)d_in[0];
    const float* points = (const float*)d_in[1];
    const float* w0 = (const float*)d_in[2];
    const float* w1 = (const float*)d_in[3];
    const float* w2 = (const float*)d_in[4];
    const float* g0 = (const float*)d_in[5];
    const float* b0 = (const float*)d_in[6];
    const float* m0 = (const float*)d_in[7];
    const float* v0 = (const float*)d_in[8];
    const float* g1 = (const float*)d_in[9];
    const float* b1 = (const float*)d_in[10];
    const float* m1 = (const float*)d_in[11];
    const float* v1 = (const float*)d_in[12];
    const float* g2 = (const float*)d_in[13];
    const float* b2 = (const float*)d_in[14];
    const float* m2 = (const float*)d_in[15];
    const float* v2 = (const float*)d_in[16];

    float* out = (float*)d_out;                       // new_xyz [8,3,2048] then new_points [8,128,2048]
    float* wb  = (float*)d_ws;                        // 16832 floats of folded weights
    int*   prog = (int*)((char*)d_ws + 128 * 1024);   // per-batch progress counters

    prep_kernel<<<32, 256, 0, stream>>>(w0, w1, w2, g0, b0, m0, v0,
                                        g1, b1, m1, v1, g2, b2, m2, v2, wb);
    fused_kernel<<<Bn + NCONS, 256, 0, stream>>>(xyz, points, wb, out,
                                                 out + Bn * 3 * Sn, prog);
}

// Round 6
// 2221.518 us; speedup vs baseline: 1.9586x; 1.0492x over previous
//
#include <hip/hip_runtime.h>
#include <math.h>

#define Bn 8
#define Nn 8192
#define Dn 64
#define Sn 2048
#define NS 32
#define NCONS 240
#define LAG 8

typedef float f2 __attribute__((ext_vector_type(2)));
typedef unsigned long long u64;

// DPP helper: returns permuted src (untouched lanes keep own value).
#define DPP_STEP(v, ctrl, rmask)                                               \
    __builtin_amdgcn_update_dpp((v), (v), (ctrl), (rmask), 0xf, false)

// Device-scope (AGENT) relaxed atomics -> coherent point (cross-XCD safe).
#define ATOMIC_ST(p, v) __hip_atomic_store((p), (v), __ATOMIC_RELAXED, __HIP_MEMORY_SCOPE_AGENT)
#define ATOMIC_LD(p)    __hip_atomic_load((p), __ATOMIC_RELAXED, __HIP_MEMORY_SCOPE_AGENT)

// LDS-only barrier: drain LDS writes, sync, and pin scheduling. Producer's
// outstanding global (publish) stores are NOT drained -> no per-iter stall on
// agent-store completion (that drain was R4's 540us regression).
#define LDS_BARRIER()                                                          \
    do {                                                                       \
        asm volatile("s_waitcnt lgkmcnt(0)" ::: "memory");                     \
        __builtin_amdgcn_s_barrier();                                          \
        __builtin_amdgcn_sched_barrier(0);                                     \
    } while (0)

// ---------------------------------------------------------------------------
// Fused producer/consumer kernel.
//  blocks 0..7   : FPS for batch b + lagged publish (coords + prog counters)
//  blocks 8..247 : consumers; block c handles samples t = c, c+240, ...
// Co-residency: ~130KB LDS -> 1 block/CU; 248 blocks <= 256 CUs -> all
// resident regardless of dispatch order -> no spin deadlock.
// prog[b] = t-LAG+1 published at iter t (LAG-iter ~6.6us lag >> store
// latency) so consumers never see a published-but-incomplete coordinate.
// Poisoned prog (0xAAAAAAAA) is negative -> consumers spin until written.
// ---------------------------------------------------------------------------
__global__ __launch_bounds__(256)
void fused_kernel(const float* __restrict__ xyz, const float* __restrict__ ptT,
                  const float* __restrict__ wb, float* __restrict__ newxyz_f,
                  float* __restrict__ outp, int* __restrict__ prog)
{
#pragma clang fp contract(off)
    __shared__ float4 lxyz[Nn];                 // 128 KB (fps role)
    __shared__ u64    ckey[2][4];
    __shared__ float4 cxyz[2][4];
    __shared__ int    lidx[4][2][NS];           // 1 KB (consumer role)
    const int tid = threadIdx.x;
    const int lane = tid & 63;
    int* newxyz_i = (int*)newxyz_f;

    if (blockIdx.x < Bn) {
        // ===================== producer: FPS =====================
        const int b = blockIdx.x;
        const int wv = tid >> 6;                // 0..3
        const float* xb = xyz + (size_t)b * 3 * Nn;
        f2 px[16], py[16], pz[16], pd[16];
        const int base = tid * 32;
#pragma unroll
        for (int q = 0; q < 8; ++q) {
            float4 vx = *(const float4*)(xb + base + 4 * q);
            float4 vy = *(const float4*)(xb + Nn + base + 4 * q);
            float4 vz = *(const float4*)(xb + 2 * Nn + base + 4 * q);
            px[2 * q]     = (f2){vx.x, vx.y};  px[2 * q + 1] = (f2){vx.z, vx.w};
            py[2 * q]     = (f2){vy.x, vy.y};  py[2 * q + 1] = (f2){vy.z, vy.w};
            pz[2 * q]     = (f2){vz.x, vz.y};  pz[2 * q + 1] = (f2){vz.z, vz.w};
            pd[2 * q]     = (f2){1e10f, 1e10f};
            pd[2 * q + 1] = (f2){1e10f, 1e10f};
            lxyz[base + 4 * q + 0] = make_float4(vx.x, vy.x, vz.x, 0.f);
            lxyz[base + 4 * q + 1] = make_float4(vx.y, vy.y, vz.y, 0.f);
            lxyz[base + 4 * q + 2] = make_float4(vx.z, vy.z, vz.z, 0.f);
            lxyz[base + 4 * q + 3] = make_float4(vx.w, vy.w, vz.w, 0.f);
        }
        float cx = xb[0], cy = xb[Nn], cz = xb[2 * Nn];
        const size_t nb0 = (size_t)b * 3 * Sn;
        if (tid == 0) {
            ATOMIC_ST(newxyz_i + nb0,          __float_as_int(cx));
            ATOMIC_ST(newxyz_i + nb0 + Sn,     __float_as_int(cy));
            ATOMIC_ST(newxyz_i + nb0 + 2 * Sn, __float_as_int(cz));
        }
        __syncthreads();

        for (int t = 1; t < Sn; ++t) {
            f2 c0 = {cx, cx}, c1 = {cy, cy}, c2 = {cz, cz};
            float best = -1.0f; int gi = 0;
#pragma unroll
            for (int i = 0; i < 16; ++i) {
                f2 dx = px[i] - c0;
                f2 dy = py[i] - c1;
                f2 dz = pz[i] - c2;
                f2 s0 = dx * dx;
                f2 s1 = dy * dy;
                f2 s2 = dz * dz;
                f2 d  = (s0 + s1) + s2;        // ((dx2+dy2)+dz2) per component
                f2 nd;
                nd.x = fminf(pd[i].x, d.x);
                nd.y = fminf(pd[i].y, d.y);
                pd[i] = nd;
                if (nd.x > best) { best = nd.x; gi = base + 2 * i; }      // strict >
                if (nd.y > best) { best = nd.y; gi = base + 2 * i + 1; }  // => first
            }
            // wave value-max via DPP (VALU pipe)
            int vb = __float_as_int(best);     // dists >= 0: bit-monotone
            { int s_;
              s_ = DPP_STEP(vb, 0x111, 0xf); vb = __float_as_int(fmaxf(__int_as_float(vb), __int_as_float(s_)));
              s_ = DPP_STEP(vb, 0x112, 0xf); vb = __float_as_int(fmaxf(__int_as_float(vb), __int_as_float(s_)));
              s_ = DPP_STEP(vb, 0x114, 0xf); vb = __float_as_int(fmaxf(__int_as_float(vb), __int_as_float(s_)));
              s_ = DPP_STEP(vb, 0x118, 0xf); vb = __float_as_int(fmaxf(__int_as_float(vb), __int_as_float(s_)));
              s_ = DPP_STEP(vb, 0x142, 0xa); vb = __float_as_int(fmaxf(__int_as_float(vb), __int_as_float(s_)));
              s_ = DPP_STEP(vb, 0x143, 0xc); vb = __float_as_int(fmaxf(__int_as_float(vb), __int_as_float(s_)));
            }
            const int smax = __builtin_amdgcn_readlane(vb, 63);
            const float wmaxf = __int_as_float(smax);
            u64 m = __ballot(best == wmaxf);
            int fl = (int)__ffsll((long long)m) - 1;     // lowest lane = smallest idx
            int gw_ = __builtin_amdgcn_readlane(gi, fl);
            if (lane == 0) {                             // publish key + coords
                float4 wc = lxyz[gw_];
                ckey[t & 1][wv] = ((u64)(unsigned)smax << 32) | (unsigned)(8191 - gw_);
                cxyz[t & 1][wv] = wc;
            }
            LDS_BARRIER();                               // LDS-only drain (no vmcnt!)
            u64 k0 = ckey[t & 1][0], k1 = ckey[t & 1][1];
            u64 k2 = ckey[t & 1][2], k3 = ckey[t & 1][3];
            float4 q0 = cxyz[t & 1][0], q1 = cxyz[t & 1][1];
            float4 q2 = cxyz[t & 1][2], q3 = cxyz[t & 1][3];
            if (k1 > k0) { k0 = k1; q0 = q1; }           // larger key wins;
            if (k3 > k2) { k2 = k3; q2 = q3; }           // tie -> smaller idx
            if (k2 > k0) { k0 = k2; q0 = q2; }
            cx = q0.x; cy = q0.y; cz = q0.z;
            if (tid == 0) {
                ATOMIC_ST(prog + b, t - (LAG - 1));      // lagged publish
                ATOMIC_ST(newxyz_i + nb0 + t,          __float_as_int(cx));
                ATOMIC_ST(newxyz_i + nb0 + Sn + t,     __float_as_int(cy));
                ATOMIC_ST(newxyz_i + nb0 + 2 * Sn + t, __float_as_int(cz));
            }
        }
        if (tid == 0) {
            asm volatile("s_waitcnt vmcnt(0)" ::: "memory");  // drain all coord stores
            ATOMIC_ST(prog + b, Sn);
        }
    } else {
        // ===================== consumer: ballq + MLP =====================
        const int cid = blockIdx.x - Bn;
        const int w = tid >> 6;                 // wave 0..3
        const float R2 = (float)(0.4 * 0.4);    // 0.15999999642f, matches numpy
        for (int t = cid; t < Sn; t += NCONS) {
            if (tid < Bn) {
                while (ATOMIC_LD(prog + tid) < t + 1) __builtin_amdgcn_s_sleep(8);
            }
            __syncthreads();
            const int myb = 2 * w + (lane >> 5);
            const size_t nb = (size_t)myb * 3 * Sn;
            const float cxm = __int_as_float(ATOMIC_LD(newxyz_i + nb + t));
            const float cym = __int_as_float(ATOMIC_LD(newxyz_i + nb + Sn + t));
            const float czm = __int_as_float(ATOMIC_LD(newxyz_i + nb + 2 * Sn + t));
            // ---- ball query: wave handles batches 2w and 2w+1 ----
#pragma unroll
            for (int h = 0; h < 2; ++h) {
                const int bq = 2 * w + h;
                const float cx = __shfl(cxm, h * 32);
                const float cy = __shfl(cym, h * 32);
                const float cz = __shfl(czm, h * 32);
                const float* xb = xyz + (size_t)bq * 3 * Nn;
                int cnt = 0, first = -1;
                for (int bs2 = 0; bs2 < Nn && cnt < NS; bs2 += 64) {
                    int jj = bs2 + lane;
                    float dx = cx - xb[jj];
                    float dy = cy - xb[Nn + jj];
                    float dz = cz - xb[2 * Nn + jj];
                    float d = (dx * dx + dy * dy) + dz * dz;
                    bool hit = d <= R2;
                    u64 m = __ballot(hit);
                    if (hit) {
                        int pos = cnt + __popcll(m & ((1ull << lane) - 1ull));
                        if (pos < NS) lidx[w][h][pos] = jj;
                    }
                    if (first < 0 && m != 0ull) first = bs2 + (int)__ffsll((long long)m) - 1;
                    cnt += (int)__popcll(m);
                }
                for (int p = cnt + lane; p < NS; p += 64) lidx[w][h][p] = first;
            }
            // ---- MLP: lanes 0-31 -> batch 2w, lanes 32-63 -> batch 2w+1 ----
            const int k = lane & 31;
            const int j = lidx[w][lane >> 5][k];
            const float* xb2 = xyz + (size_t)myb * 3 * Nn;
            const float x0 = xb2[j]          - cxm;
            const float x1 = xb2[Nn + j]     - cym;
            const float x2 = xb2[2 * Nn + j] - czm;
            // transposed points: ptT[b][j][d] contiguous in d -> 16 dwordx4
            const float* pb = ptT + ((size_t)myb * Nn + j) * Dn;
            float xf[64];
#pragma unroll
            for (int d0 = 0; d0 < 64; d0 += 4) {
                float4 v = *(const float4*)(pb + d0);
                xf[d0] = v.x; xf[d0 + 1] = v.y; xf[d0 + 2] = v.z; xf[d0 + 3] = v.w;
            }

            const float* w0  = wb;
            const float* bb0 = wb + 64 * 67;
            float h0[64];
#pragma unroll 2
            for (int c = 0; c < 64; ++c) {
                const float* wr = w0 + c * 67;
                float a0 = fmaf(wr[0], x0, bb0[c]);
                float a1 = wr[1] * x1;
                float a2 = wr[2] * x2;
                float a3 = 0.0f;
#pragma unroll
                for (int d = 0; d < 64; d += 4) {
                    a0 = fmaf(wr[3 + d], xf[d],     a0);
                    a1 = fmaf(wr[4 + d], xf[d + 1], a1);
                    a2 = fmaf(wr[5 + d], xf[d + 2], a2);
                    a3 = fmaf(wr[6 + d], xf[d + 3], a3);
                }
                h0[c] = fmaxf((a0 + a1) + (a2 + a3), 0.0f);
            }
            const float* w1  = wb + 4352;
            const float* bb1 = wb + 8448;
            float h1[64];
#pragma unroll 2
            for (int c = 0; c < 64; ++c) {
                const float* wr = w1 + c * 64;
                float a0 = bb1[c], a1 = 0.f, a2 = 0.f, a3 = 0.f;
#pragma unroll
                for (int d = 0; d < 64; d += 4) {
                    a0 = fmaf(wr[d],     h0[d],     a0);
                    a1 = fmaf(wr[d + 1], h0[d + 1], a1);
                    a2 = fmaf(wr[d + 2], h0[d + 2], a2);
                    a3 = fmaf(wr[d + 3], h0[d + 3], a3);
                }
                h1[c] = fmaxf((a0 + a1) + (a2 + a3), 0.0f);
            }
            const float* w2  = wb + 8512;
            const float* bb2 = wb + 16704;
            float* ob = outp + ((size_t)myb * 128) * Sn + t;
#pragma unroll 2
            for (int c = 0; c < 128; ++c) {
                const float* wr = w2 + c * 64;
                float a0 = bb2[c], a1 = 0.f, a2 = 0.f, a3 = 0.f;
#pragma unroll
                for (int d = 0; d < 64; d += 4) {
                    a0 = fmaf(wr[d],     h1[d],     a0);
                    a1 = fmaf(wr[d + 1], h1[d + 1], a1);
                    a2 = fmaf(wr[d + 2], h1[d + 2], a2);
                    a3 = fmaf(wr[d + 3], h1[d + 3], a3);
                }
                float acc = fmaxf((a0 + a1) + (a2 + a3), 0.0f);
#pragma unroll
                for (int off = 1; off < 32; off <<= 1) acc = fmaxf(acc, __shfl_xor(acc, off));
                if (k == 0) ob[(size_t)c * Sn] = acc;
            }
        }
    }
}

// ---------------------------------------------------------------------------
// Tile-transpose points [B,D,N] -> ptT [B,N,D]. 64x64 tiles via LDS (+1 pad).
// ---------------------------------------------------------------------------
__global__ __launch_bounds__(256)
void tr_kernel(const float* __restrict__ pts, float* __restrict__ ptT)
{
    __shared__ float tile[64][65];
    const int bid = blockIdx.x;
    const int b = bid >> 7;                 // Nn/64 = 128 tiles per batch
    const int j0 = (bid & 127) * 64;
    const int lane = threadIdx.x & 63;
    const int w = threadIdx.x >> 6;         // 4 waves
    const float* src = pts + (size_t)b * Dn * Nn;
#pragma unroll
    for (int d = w * 16; d < w * 16 + 16; ++d)
        tile[d][lane] = src[(size_t)d * Nn + j0 + lane];
    __syncthreads();
    float* dst = ptT + ((size_t)b * Nn + j0) * Dn;
#pragma unroll
    for (int jj = w * 16; jj < w * 16 + 16; ++jj)
        dst[(size_t)jj * Dn + lane] = tile[lane][jj];
}

// ---------------------------------------------------------------------------
// Fold BN (eval) into conv weights: wf = w*scale_c, bias = b - m*scale_c.
// ---------------------------------------------------------------------------
__global__ void prep_kernel(const float* __restrict__ w0, const float* __restrict__ w1,
                            const float* __restrict__ w2,
                            const float* __restrict__ g0, const float* __restrict__ b0,
                            const float* __restrict__ m0, const float* __restrict__ v0,
                            const float* __restrict__ g1, const float* __restrict__ b1,
                            const float* __restrict__ m1, const float* __restrict__ v1,
                            const float* __restrict__ g2, const float* __restrict__ b2,
                            const float* __restrict__ m2, const float* __restrict__ v2,
                            float* __restrict__ wb)
{
    int t = blockIdx.x * blockDim.x + threadIdx.x;
    if (t < 64 * 67) { int c = t / 67; float sc = g0[c] / sqrtf(v0[c] + 1e-5f); wb[t] = w0[t] * sc; }
    if (t < 64)      { float sc = g0[t] / sqrtf(v0[t] + 1e-5f); wb[4288 + t] = b0[t] - m0[t] * sc; }
    if (t < 64 * 64) { int c = t / 64; float sc = g1[c] / sqrtf(v1[c] + 1e-5f); wb[4352 + t] = w1[t] * sc; }
    if (t < 64)      { float sc = g1[t] / sqrtf(v1[t] + 1e-5f); wb[8448 + t] = b1[t] - m1[t] * sc; }
    if (t < 128 * 64){ int c = t / 64; float sc = g2[c] / sqrtf(v2[c] + 1e-5f); wb[8512 + t] = w2[t] * sc; }
    if (t < 128)     { float sc = g2[t] / sqrtf(v2[t] + 1e-5f); wb[16704 + t] = b2[t] - m2[t] * sc; }
}

extern "C" void kernel_launch(void* const* d_in, const int* in_sizes, int n_in,
                              void* d_out, int out_size, void* d_ws, size_t ws_size,
                              hipStream_t stream)
{
    const float* xyz    = (const float*)d_in[0];
    const float* points = (const float*)d_in[1];
    const float* w0 = (const float*)d_in[2];
    const float* w1 = (const float*)d_in[3];
    const float* w2 = (const float*)d_in[4];
    const float* g0 = (const float*)d_in[5];
    const float* b0 = (const float*)d_in[6];
    const float* m0 = (const float*)d_in[7];
    const float* v0 = (const float*)d_in[8];
    const float* g1 = (const float*)d_in[9];
    const float* b1 = (const float*)d_in[10];
    const float* m1 = (const float*)d_in[11];
    const float* v1 = (const float*)d_in[12];
    const float* g2 = (const float*)d_in[13];
    const float* b2 = (const float*)d_in[14];
    const float* m2 = (const float*)d_in[15];
    const float* v2 = (const float*)d_in[16];

    float* out  = (float*)d_out;                       // new_xyz [8,3,2048] then new_points [8,128,2048]
    float* wb   = (float*)d_ws;                        // 16832 floats of folded weights
    int*   prog = (int*)((char*)d_ws + 128 * 1024);    // per-batch progress counters
    float* ptT  = (float*)((char*)d_ws + 192 * 1024);  // transposed points [B,N,D] = 16.78 MB

    prep_kernel<<<32, 256, 0, stream>>>(w0, w1, w2, g0, b0, m0, v0,
                                        g1, b1, m1, v1, g2, b2, m2, v2, wb);
    tr_kernel<<<Bn * (Nn / 64), 256, 0, stream>>>(points, ptT);
    fused_kernel<<<Bn + NCONS, 256, 0, stream>>>(xyz, ptT, wb, out,
                                                 out + Bn * 3 * Sn, prog);
}

// Round 7
// 2101.106 us; speedup vs baseline: 2.0709x; 1.0573x over previous
//
#include <hip/hip_runtime.h>
#include <math.h>

#define Bn 8
#define Nn 8192
#define Dn 64
#define Sn 2048
#define NS 32
#define NCONS 240
#define LAG 8
#define PSTR 64   // prog padding: one 256B line per batch counter

typedef float f2 __attribute__((ext_vector_type(2)));
typedef unsigned long long u64;

// DPP helper: returns permuted src (untouched lanes keep own value).
#define DPP_STEP(v, ctrl, rmask)                                               \
    __builtin_amdgcn_update_dpp((v), (v), (ctrl), (rmask), 0xf, false)

// Device-scope (AGENT) relaxed atomics -> coherent point (cross-XCD safe).
#define ATOMIC_ST(p, v) __hip_atomic_store((p), (v), __ATOMIC_RELAXED, __HIP_MEMORY_SCOPE_AGENT)
#define ATOMIC_LD(p)    __hip_atomic_load((p), __ATOMIC_RELAXED, __HIP_MEMORY_SCOPE_AGENT)

// LDS-only barrier: drain LDS, sync, pin scheduling; do NOT drain vmem
// (producer's publish stores stay in flight -> no per-iter store-latency stall).
#define LDS_BARRIER()                                                          \
    do {                                                                       \
        asm volatile("s_waitcnt lgkmcnt(0)" ::: "memory");                     \
        __builtin_amdgcn_s_barrier();                                          \
        __builtin_amdgcn_sched_barrier(0);                                     \
    } while (0)

// ---------------------------------------------------------------------------
// Single fused kernel.
//  blocks 0..7   : FPS producer for batch b + lagged publish (sc1 stores)
//  blocks 8..247 : consumers. Startup: transpose points [B,D,N]->ptT[B,N,D]
//                  (sc1 write-through stores), block 8 also folds BN->wb;
//                  vmcnt(0) drain -> fetch_add(done) -> spin done==240.
//                  Then per sample t (grid-stride): spin padded prog, ballq,
//                  MLP, maxpool.
// Co-residency: ~130KB LDS -> 1 block/CU; 248 blocks <= 256 CUs -> all
// resident regardless of dispatch order -> spins cannot deadlock.
// Visibility: sc1 stores/loads bypass non-coherent per-XCD L2s; plain reads
// of ptT/wb happen only after the done handshake, and all L2s start the
// kernel invalidated (AQL acquire) -> no stale lines possible.
// prog[b*PSTR] = t-LAG+1 published at iter t (~6.8us lag >> store latency).
// ---------------------------------------------------------------------------
__global__ __launch_bounds__(256)
void fused_kernel(const float* __restrict__ xyz, const float* __restrict__ pts,
                  float* __restrict__ wb, float* __restrict__ newxyz_f,
                  float* __restrict__ outp, int* __restrict__ prog,
                  int* __restrict__ done, float* __restrict__ ptT,
                  const float* __restrict__ w0g, const float* __restrict__ w1g,
                  const float* __restrict__ w2g,
                  const float* __restrict__ g0, const float* __restrict__ b0,
                  const float* __restrict__ m0, const float* __restrict__ v0,
                  const float* __restrict__ g1, const float* __restrict__ b1,
                  const float* __restrict__ m1, const float* __restrict__ v1,
                  const float* __restrict__ g2, const float* __restrict__ b2,
                  const float* __restrict__ m2, const float* __restrict__ v2)
{
#pragma clang fp contract(off)
    __shared__ float4 lxyz[Nn];                 // 128 KB (fps) / transpose tile alias
    __shared__ u64    ckey[2][4];
    __shared__ float4 cxyz[2][4];
    __shared__ int    lidx[4][2][NS];           // 1 KB (consumer)
    const int tid = threadIdx.x;
    const int lane = tid & 63;
    int* newxyz_i = (int*)newxyz_f;

    if (blockIdx.x < Bn) {
        // ===================== producer: FPS =====================
        const int b = blockIdx.x;
        const int wv = tid >> 6;                // 0..3
        const float* xb = xyz + (size_t)b * 3 * Nn;
        f2 px[16], py[16], pz[16], pd[16];
        const int base = tid * 32;
#pragma unroll
        for (int q = 0; q < 8; ++q) {
            float4 vx = *(const float4*)(xb + base + 4 * q);
            float4 vy = *(const float4*)(xb + Nn + base + 4 * q);
            float4 vz = *(const float4*)(xb + 2 * Nn + base + 4 * q);
            px[2 * q]     = (f2){vx.x, vx.y};  px[2 * q + 1] = (f2){vx.z, vx.w};
            py[2 * q]     = (f2){vy.x, vy.y};  py[2 * q + 1] = (f2){vy.z, vy.w};
            pz[2 * q]     = (f2){vz.x, vz.y};  pz[2 * q + 1] = (f2){vz.z, vz.w};
            pd[2 * q]     = (f2){1e10f, 1e10f};
            pd[2 * q + 1] = (f2){1e10f, 1e10f};
            lxyz[base + 4 * q + 0] = make_float4(vx.x, vy.x, vz.x, 0.f);
            lxyz[base + 4 * q + 1] = make_float4(vx.y, vy.y, vz.y, 0.f);
            lxyz[base + 4 * q + 2] = make_float4(vx.z, vy.z, vz.z, 0.f);
            lxyz[base + 4 * q + 3] = make_float4(vx.w, vy.w, vz.w, 0.f);
        }
        float cx = xb[0], cy = xb[Nn], cz = xb[2 * Nn];
        const size_t nb0 = (size_t)b * 3 * Sn;
        if (tid == 0) {
            ATOMIC_ST(newxyz_i + nb0,          __float_as_int(cx));
            ATOMIC_ST(newxyz_i + nb0 + Sn,     __float_as_int(cy));
            ATOMIC_ST(newxyz_i + nb0 + 2 * Sn, __float_as_int(cz));
        }
        __syncthreads();

        for (int t = 1; t < Sn; ++t) {
            f2 c0 = {cx, cx}, c1 = {cy, cy}, c2 = {cz, cz};
            float best = -1.0f; int gi = 0;
#pragma unroll
            for (int i = 0; i < 16; ++i) {
                f2 dx = px[i] - c0;
                f2 dy = py[i] - c1;
                f2 dz = pz[i] - c2;
                f2 s0 = dx * dx;
                f2 s1 = dy * dy;
                f2 s2 = dz * dz;
                f2 d  = (s0 + s1) + s2;        // ((dx2+dy2)+dz2) per component
                f2 nd;
                nd.x = fminf(pd[i].x, d.x);
                nd.y = fminf(pd[i].y, d.y);
                pd[i] = nd;
                if (nd.x > best) { best = nd.x; gi = base + 2 * i; }      // strict >
                if (nd.y > best) { best = nd.y; gi = base + 2 * i + 1; }  // => first
            }
            // wave value-max via DPP (VALU pipe)
            int vb = __float_as_int(best);     // dists >= 0: bit-monotone
            { int s_;
              s_ = DPP_STEP(vb, 0x111, 0xf); vb = __float_as_int(fmaxf(__int_as_float(vb), __int_as_float(s_)));
              s_ = DPP_STEP(vb, 0x112, 0xf); vb = __float_as_int(fmaxf(__int_as_float(vb), __int_as_float(s_)));
              s_ = DPP_STEP(vb, 0x114, 0xf); vb = __float_as_int(fmaxf(__int_as_float(vb), __int_as_float(s_)));
              s_ = DPP_STEP(vb, 0x118, 0xf); vb = __float_as_int(fmaxf(__int_as_float(vb), __int_as_float(s_)));
              s_ = DPP_STEP(vb, 0x142, 0xa); vb = __float_as_int(fmaxf(__int_as_float(vb), __int_as_float(s_)));
              s_ = DPP_STEP(vb, 0x143, 0xc); vb = __float_as_int(fmaxf(__int_as_float(vb), __int_as_float(s_)));
            }
            const int smax = __builtin_amdgcn_readlane(vb, 63);
            const float wmaxf = __int_as_float(smax);
            u64 m = __ballot(best == wmaxf);
            int fl = (int)__ffsll((long long)m) - 1;     // lowest lane = smallest idx
            int gw_ = __builtin_amdgcn_readlane(gi, fl);
            if (lane == 0) {                             // publish key + coords
                float4 wc = lxyz[gw_];
                ckey[t & 1][wv] = ((u64)(unsigned)smax << 32) | (unsigned)(8191 - gw_);
                cxyz[t & 1][wv] = wc;
            }
            LDS_BARRIER();                               // LDS-only drain (no vmcnt)
            u64 k0 = ckey[t & 1][0], k1 = ckey[t & 1][1];
            u64 k2 = ckey[t & 1][2], k3 = ckey[t & 1][3];
            float4 q0 = cxyz[t & 1][0], q1 = cxyz[t & 1][1];
            float4 q2 = cxyz[t & 1][2], q3 = cxyz[t & 1][3];
            if (k1 > k0) { k0 = k1; q0 = q1; }           // larger key wins;
            if (k3 > k2) { k2 = k3; q2 = q3; }           // tie -> smaller idx
            if (k2 > k0) { k0 = k2; q0 = q2; }
            cx = q0.x; cy = q0.y; cz = q0.z;
            if (tid == 0) {
                ATOMIC_ST(prog + b * PSTR, t - (LAG - 1));   // lagged publish
                ATOMIC_ST(newxyz_i + nb0 + t,          __float_as_int(cx));
                ATOMIC_ST(newxyz_i + nb0 + Sn + t,     __float_as_int(cy));
                ATOMIC_ST(newxyz_i + nb0 + 2 * Sn + t, __float_as_int(cz));
            }
        }
        if (tid == 0) {
            asm volatile("s_waitcnt vmcnt(0)" ::: "memory");  // drain coord stores
            ATOMIC_ST(prog + b * PSTR, Sn);
        }
    } else {
        // ===================== consumer =====================
        const int cid = blockIdx.x - Bn;
        const int w = tid >> 6;                 // wave 0..3
        // ---- startup phase: transpose (+ BN fold by block cid==0) ----
        {
            float (*tile)[65] = (float (*)[65])lxyz;
            for (int tb = cid; tb < Bn * (Nn / 64); tb += NCONS) {
                const int b = tb >> 7;
                const int j0 = (tb & 127) << 6;
                const float* src = pts + (size_t)b * Dn * Nn;
#pragma unroll
                for (int i = 0; i < 16; ++i) {
                    int d = w * 16 + i;
                    tile[d][lane] = src[(size_t)d * Nn + j0 + lane];
                }
                __syncthreads();
                float* dst = ptT + ((size_t)b * Nn + j0) * Dn;
#pragma unroll
                for (int i = 0; i < 16; ++i) {
                    int jj = w * 16 + i;
                    ATOMIC_ST((int*)(dst + (size_t)jj * Dn + lane),
                              __float_as_int(tile[lane][jj]));
                }
                __syncthreads();
            }
            if (cid == 0) {                     // fold BN into weights -> wb
                for (int u = tid; u < 8192; u += 256) {
                    if (u < 4288) { int c = u / 67; float sc = g0[c] / sqrtf(v0[c] + 1e-5f);
                                    ATOMIC_ST((int*)(wb + u), __float_as_int(w0g[u] * sc)); }
                    if (u < 64)   { float sc = g0[u] / sqrtf(v0[u] + 1e-5f);
                                    ATOMIC_ST((int*)(wb + 4288 + u), __float_as_int(b0[u] - m0[u] * sc)); }
                    if (u < 4096) { int c = u / 64; float sc = g1[c] / sqrtf(v1[c] + 1e-5f);
                                    ATOMIC_ST((int*)(wb + 4352 + u), __float_as_int(w1g[u] * sc)); }
                    if (u < 64)   { float sc = g1[u] / sqrtf(v1[u] + 1e-5f);
                                    ATOMIC_ST((int*)(wb + 8448 + u), __float_as_int(b1[u] - m1[u] * sc)); }
                    if (u < 8192) { int c = u / 64; float sc = g2[c] / sqrtf(v2[c] + 1e-5f);
                                    ATOMIC_ST((int*)(wb + 8512 + u), __float_as_int(w2g[u] * sc)); }
                    if (u < 128)  { float sc = g2[u] / sqrtf(v2[u] + 1e-5f);
                                    ATOMIC_ST((int*)(wb + 16704 + u), __float_as_int(b2[u] - m2[u] * sc)); }
                }
            }
            asm volatile("s_waitcnt vmcnt(0)" ::: "memory");  // every thread drains
            __syncthreads();
            if (tid == 0) {
                __hip_atomic_fetch_add(done, 1, __ATOMIC_RELAXED, __HIP_MEMORY_SCOPE_AGENT);
                while (ATOMIC_LD(done) != NCONS) __builtin_amdgcn_s_sleep(32);
            }
            __syncthreads();
        }
        // ---- main loop: ballq + MLP per sample t ----
        const float R2 = (float)(0.4 * 0.4);    // 0.15999999642f, matches numpy
        for (int t = cid; t < Sn; t += NCONS) {
            if (tid < Bn) {
                while (ATOMIC_LD(prog + tid * PSTR) < t + 1) __builtin_amdgcn_s_sleep(32);
            }
            __syncthreads();
            const int myb = 2 * w + (lane >> 5);
            const size_t nb = (size_t)myb * 3 * Sn;
            const float cxm = __int_as_float(ATOMIC_LD(newxyz_i + nb + t));
            const float cym = __int_as_float(ATOMIC_LD(newxyz_i + nb + Sn + t));
            const float czm = __int_as_float(ATOMIC_LD(newxyz_i + nb + 2 * Sn + t));
            // ---- ball query: wave handles batches 2w and 2w+1 ----
#pragma unroll
            for (int h = 0; h < 2; ++h) {
                const int bq = 2 * w + h;
                const float cx = __shfl(cxm, h * 32);
                const float cy = __shfl(cym, h * 32);
                const float cz = __shfl(czm, h * 32);
                const float* xb = xyz + (size_t)bq * 3 * Nn;
                int cnt = 0, first = -1;
                for (int bs2 = 0; bs2 < Nn && cnt < NS; bs2 += 64) {
                    int jj = bs2 + lane;
                    float dx = cx - xb[jj];
                    float dy = cy - xb[Nn + jj];
                    float dz = cz - xb[2 * Nn + jj];
                    float d = (dx * dx + dy * dy) + dz * dz;
                    bool hit = d <= R2;
                    u64 m = __ballot(hit);
                    if (hit) {
                        int pos = cnt + __popcll(m & ((1ull << lane) - 1ull));
                        if (pos < NS) lidx[w][h][pos] = jj;
                    }
                    if (first < 0 && m != 0ull) first = bs2 + (int)__ffsll((long long)m) - 1;
                    cnt += (int)__popcll(m);
                }
                for (int p = cnt + lane; p < NS; p += 64) lidx[w][h][p] = first;
            }
            // ---- MLP: lanes 0-31 -> batch 2w, lanes 32-63 -> batch 2w+1 ----
            const int k = lane & 31;
            const int j = lidx[w][lane >> 5][k];
            const float* xb2 = xyz + (size_t)myb * 3 * Nn;
            const float x0 = xb2[j]          - cxm;
            const float x1 = xb2[Nn + j]     - cym;
            const float x2 = xb2[2 * Nn + j] - czm;
            const float* pb = ptT + ((size_t)myb * Nn + j) * Dn;
            float xf[64];
#pragma unroll
            for (int d0 = 0; d0 < 64; d0 += 4) {
                float4 v = *(const float4*)(pb + d0);
                xf[d0] = v.x; xf[d0 + 1] = v.y; xf[d0 + 2] = v.z; xf[d0 + 3] = v.w;
            }

            const float* w0  = wb;
            const float* bb0 = wb + 64 * 67;
            float h0[64];
#pragma unroll 2
            for (int c = 0; c < 64; ++c) {
                const float* wr = w0 + c * 67;
                float a0 = fmaf(wr[0], x0, bb0[c]);
                float a1 = wr[1] * x1;
                float a2 = wr[2] * x2;
                float a3 = 0.0f;
#pragma unroll
                for (int d = 0; d < 64; d += 4) {
                    a0 = fmaf(wr[3 + d], xf[d],     a0);
                    a1 = fmaf(wr[4 + d], xf[d + 1], a1);
                    a2 = fmaf(wr[5 + d], xf[d + 2], a2);
                    a3 = fmaf(wr[6 + d], xf[d + 3], a3);
                }
                h0[c] = fmaxf((a0 + a1) + (a2 + a3), 0.0f);
            }
            const float* w1  = wb + 4352;
            const float* bb1 = wb + 8448;
            float h1[64];
#pragma unroll 2
            for (int c = 0; c < 64; ++c) {
                const float* wr = w1 + c * 64;
                float a0 = bb1[c], a1 = 0.f, a2 = 0.f, a3 = 0.f;
#pragma unroll
                for (int d = 0; d < 64; d += 4) {
                    a0 = fmaf(wr[d],     h0[d],     a0);
                    a1 = fmaf(wr[d + 1], h0[d + 1], a1);
                    a2 = fmaf(wr[d + 2], h0[d + 2], a2);
                    a3 = fmaf(wr[d + 3], h0[d + 3], a3);
                }
                h1[c] = fmaxf((a0 + a1) + (a2 + a3), 0.0f);
            }
            const float* w2  = wb + 8512;
            const float* bb2 = wb + 16704;
            float* ob = outp + ((size_t)myb * 128) * Sn + t;
#pragma unroll 2
            for (int c = 0; c < 128; ++c) {
                const float* wr = w2 + c * 64;
                float a0 = bb2[c], a1 = 0.f, a2 = 0.f, a3 = 0.f;
#pragma unroll
                for (int d = 0; d < 64; d += 4) {
                    a0 = fmaf(wr[d],     h1[d],     a0);
                    a1 = fmaf(wr[d + 1], h1[d + 1], a1);
                    a2 = fmaf(wr[d + 2], h1[d + 2], a2);
                    a3 = fmaf(wr[d + 3], h1[d + 3], a3);
                }
                float acc = fmaxf((a0 + a1) + (a2 + a3), 0.0f);
#pragma unroll
                for (int off = 1; off < 32; off <<= 1) acc = fmaxf(acc, __shfl_xor(acc, off));
                if (k == 0) ob[(size_t)c * Sn] = acc;
            }
        }
    }
}

extern "C" void kernel_launch(void* const* d_in, const int* in_sizes, int n_in,
                              void* d_out, int out_size, void* d_ws, size_t ws_size,
                              hipStream_t stream)
{
    const float* xyz    = (const float*)d_in[0];
    const float* points = (const float*)d_in[1];
    const float* w0 = (const float*)d_in[2];
    const float* w1 = (const float*)d_in[3];
    const float* w2 = (const float*)d_in[4];
    const float* g0 = (const float*)d_in[5];
    const float* b0 = (const float*)d_in[6];
    const float* m0 = (const float*)d_in[7];
    const float* v0 = (const float*)d_in[8];
    const float* g1 = (const float*)d_in[9];
    const float* b1 = (const float*)d_in[10];
    const float* m1 = (const float*)d_in[11];
    const float* v1 = (const float*)d_in[12];
    const float* g2 = (const float*)d_in[13];
    const float* b2 = (const float*)d_in[14];
    const float* m2 = (const float*)d_in[15];
    const float* v2 = (const float*)d_in[16];

    float* out  = (float*)d_out;                       // new_xyz [8,3,2048] then new_points [8,128,2048]
    float* wb   = (float*)d_ws;                        // 16832 floats of folded weights
    int*   prog = (int*)((char*)d_ws + 128 * 1024);    // padded per-batch progress (8 x 256B)
    int*   done = (int*)((char*)d_ws + 128 * 1024 + 2048);  // startup handshake counter
    float* ptT  = (float*)((char*)d_ws + 192 * 1024);  // transposed points [B,N,D] = 16.78 MB

    hipMemsetAsync((char*)d_ws + 128 * 1024, 0, 4096, stream);  // zero prog + done
    fused_kernel<<<Bn + NCONS, 256, 0, stream>>>(
        xyz, points, wb, out, out + Bn * 3 * Sn, prog, done, ptT,
        w0, w1, w2, g0, b0, m0, v0, g1, b1, m1, v1, g2, b2, m2, v2);
}